// Round 7
// baseline (2468.556 us; speedup 1.0000x reference)
//
#include <hip/hip_runtime.h>
#include <cfloat>

#define N_PTS 4096
#define NB    4
#define KNN   20
#define EPSB  1e-5f

#define BT 64
#define KT 16

typedef short s8v __attribute__((ext_vector_type(8)));
typedef float f4v __attribute__((ext_vector_type(4)));

// ---------------------------------------------------------------------------
// Generic K-major GEMM: Out[row][col] = sum_k Mr[k][row] * Mc[k][col]
// mode 0: plain  | mode 1: +aux1[col] | mode 2: lrelu(val+aux1[row])
// ---------------------------------------------------------------------------
__global__ __launch_bounds__(256)
void gemm_kmajor(const float* __restrict__ Mr, const float* __restrict__ Mc,
                 float* __restrict__ Out,
                 const float* __restrict__ aux1,
                 int K, int ldr, int ldc, int ldo,
                 long bsR, long bsC, long bsO,
                 int mode)
{
    __shared__ float Rs[KT][BT];
    __shared__ float Cs[KT][BT];
    int bz = blockIdx.z;
    const float* mr = Mr + bz * bsR;
    const float* mc = Mc + bz * bsC;
    float* outp = Out + bz * bsO;
    int row0 = blockIdx.x * BT;
    int col0 = blockIdx.y * BT;
    int tid = threadIdx.x;
    int tx = tid & 15, ty = tid >> 4;

    float acc[4][4];
#pragma unroll
    for (int r = 0; r < 4; r++)
#pragma unroll
        for (int c = 0; c < 4; c++) acc[r][c] = 0.f;

    for (int k0 = 0; k0 < K; k0 += KT) {
#pragma unroll
        for (int l = 0; l < (KT * BT) / 256; l++) {
            int e = l * 256 + tid;
            int kk = e >> 6, r = e & 63;
            int kg = k0 + kk;
            float rv = 0.f, cv = 0.f;
            if (kg < K) {
                rv = mr[(long)kg * ldr + row0 + r];
                cv = mc[(long)kg * ldc + col0 + r];
            }
            Rs[kk][r] = rv;
            Cs[kk][r] = cv;
        }
        __syncthreads();
#pragma unroll
        for (int kk = 0; kk < KT; kk++) {
            float rv[4], cv[4];
#pragma unroll
            for (int e = 0; e < 4; e++) rv[e] = Rs[kk][ty * 4 + e];
#pragma unroll
            for (int e = 0; e < 4; e++) cv[e] = Cs[kk][tx * 4 + e];
#pragma unroll
            for (int r = 0; r < 4; r++)
#pragma unroll
                for (int c = 0; c < 4; c++)
                    acc[r][c] = fmaf(rv[r], cv[c], acc[r][c]);
        }
        __syncthreads();
    }

    int orow = row0 + ty * 4;
    int ocol = col0 + tx * 4;
#pragma unroll
    for (int r = 0; r < 4; r++) {
        float vv[4];
#pragma unroll
        for (int c = 0; c < 4; c++) {
            float val = acc[r][c];
            if (mode == 1) {
                val += aux1[ocol + c];
            } else if (mode == 2) {
                val += aux1[orow + r];
                val = val >= 0.f ? val : 0.2f * val;
            }
            vv[c] = val;
        }
        float4 v4;
        v4.x = vv[0]; v4.y = vv[1]; v4.z = vv[2]; v4.w = vv[3];
        *(float4*)(outp + (long)(orow + r) * ldo + ocol) = v4;
    }
}

// ---------------------------------------------------------------------------
// Sorted top-20 register insert (strict <, stable: earlier/lower index wins).
// ---------------------------------------------------------------------------
__device__ __forceinline__ void insert20(float dv, int ci,
                                         float (&d20)[KNN], int (&i20)[KNN])
{
#pragma unroll
    for (int j2 = KNN - 1; j2 >= 1; j2--) {
        float pm = d20[j2 - 1]; int im = i20[j2 - 1];
        bool sh  = dv < pm;
        bool ins = (!sh) && (dv < d20[j2]);
        d20[j2] = sh ? pm : (ins ? dv : d20[j2]);
        i20[j2] = sh ? im : (ins ? ci : i20[j2]);
    }
    if (dv < d20[0]) { d20[0] = dv; i20[0] = ci; }
}

// ---------------------------------------------------------------------------
// fp32 -> bf16 hi/lo split, transposed to [b][point][k] (MFMA fragment order).
// grid (N/64, B), block 256 (64 points x 4 k-octets). k >= C zero-filled.
// ---------------------------------------------------------------------------
__global__ __launch_bounds__(256)
void to_bf16_tr(const float* __restrict__ F, long bsF, int C, int KDP,
                unsigned short* __restrict__ Ghi, unsigned short* __restrict__ Glo)
{
    int b = blockIdx.y;
    int n = blockIdx.x * 64 + (threadIdx.x & 63);
    int kq = threadIdx.x >> 6;
    const float* Fb = F + (long)b * bsF;
    for (int k0 = kq * 8; k0 < KDP; k0 += 32) {
        s8v hv, lv;
#pragma unroll
        for (int i = 0; i < 8; i++) {
            int k = k0 + i;
            float x = (k < C) ? Fb[(long)k * N_PTS + n] : 0.f;
            unsigned u = __builtin_bit_cast(unsigned, x);
            unsigned hb = (u + 0x7fffu + ((u >> 16) & 1u)) >> 16;
            float hf = __builtin_bit_cast(float, hb << 16);
            float res = x - hf;
            unsigned u2 = __builtin_bit_cast(unsigned, res);
            unsigned lb = (u2 + 0x7fffu + ((u2 >> 16) & 1u)) >> 16;
            hv[i] = (short)hb;
            lv[i] = (short)lb;
        }
        long o = ((long)b * N_PTS + n) * KDP + k0;
        *(s8v*)&Ghi[o] = hv;
        *(s8v*)&Glo[o] = lv;
    }
}

// ---------------------------------------------------------------------------
// MFMA fused distance + top-20.
// grid (N/64, 4 quarters, B), block 256 (4 independent waves, no barriers).
// Wave w: 16 queries (q0+w*16..+15) x 1024 quarter-candidates.
// Inner products: 3x mfma_f32_16x16x32_bf16 per k-step (hi*hi + hi*lo + lo*hi)
// from G arrays in [point][k] bf16 layout (A frag: m=lane&15, k=quad*8+j;
// B frag: n=lane&15, k=quad*8+j; C/D: col(n)=lane&15, row(m)=quad*4+reg).
// Distances (exact fp32 xx terms) land in per-wave LDS tile [16][68]
// (<=2-way banked); per 64-candidate chunk the 16 owner lanes scan their row
// with 16x ds_read_b128 + tau-gated sorted insert. No ballots, no shfl.
// Out: knnd/knni [b][quart][N][KNN] sorted ascending.
// ---------------------------------------------------------------------------
template<int KDP>
__global__ __launch_bounds__(256)
void fused_knn_mfma(const unsigned short* __restrict__ Ghi,
                    const unsigned short* __restrict__ Glo,
                    const float* __restrict__ xx,
                    float* __restrict__ knnd, int* __restrict__ knni)
{
    constexpr int KS = KDP / 32;
    __shared__ float dts[4][16][68];
    int tid = threadIdx.x;
    int w = tid >> 6, L = tid & 63;
    int m = L & 15, quad = L >> 4;
    int b = blockIdx.z, quart = blockIdx.y;
    int q0 = blockIdx.x * 64, qw = w * 16;
    const unsigned short* Gh = Ghi + (long)b * N_PTS * KDP;
    const unsigned short* Gl = Glo + (long)b * N_PTS * KDP;
    const float* xxb = xx + (long)b * N_PTS;

    // A fragments (this wave's 16 queries), hi+lo, all k-steps
    s8v ahi[KS], alo[KS];
    long abase = (long)(q0 + qw + m) * KDP + quad * 8;
#pragma unroll
    for (int ks = 0; ks < KS; ks++) {
        ahi[ks] = *(const s8v*)&Gh[abase + ks * 32];
        alo[ks] = *(const s8v*)&Gl[abase + ks * 32];
    }
    float xq[4];
#pragma unroll
    for (int r = 0; r < 4; r++) xq[r] = xxb[q0 + qw + quad * 4 + r];

    float d20[KNN]; int i20[KNN];
#pragma unroll
    for (int j = 0; j < KNN; j++) { d20[j] = FLT_MAX; i20[j] = 0; }

    for (int ch = 0; ch < 16; ch++) {
#pragma unroll
        for (int ct = 0; ct < 4; ct++) {
            int n0 = quart * 1024 + ch * 64 + ct * 16;
            f4v acc = {0.f, 0.f, 0.f, 0.f};
            long bbase = (long)(n0 + m) * KDP + quad * 8;
#pragma unroll
            for (int ks = 0; ks < KS; ks++) {
                s8v bhi = *(const s8v*)&Gh[bbase + ks * 32];
                s8v blo = *(const s8v*)&Gl[bbase + ks * 32];
                acc = __builtin_amdgcn_mfma_f32_16x16x32_bf16(ahi[ks], bhi, acc, 0, 0, 0);
                acc = __builtin_amdgcn_mfma_f32_16x16x32_bf16(ahi[ks], blo, acc, 0, 0, 0);
                acc = __builtin_amdgcn_mfma_f32_16x16x32_bf16(alo[ks], bhi, acc, 0, 0, 0);
            }
            float xc = xxb[n0 + m];
#pragma unroll
            for (int r = 0; r < 4; r++)
                dts[w][quad * 4 + r][ct * 16 + m] = xq[r] + xc - 2.f * acc[r];
        }
        // owner scan: lane L<16 owns query q0+qw+L == dts row L (same wave,
        // in-order DS ops + conservative lgkm waits -> no barrier needed)
        if (L < 16) {
            const float* row = dts[w][L];
            int cb = quart * 1024 + ch * 64;
            for (int g = 0; g < 16; g++) {
                float4 v4 = *(const float4*)&row[g * 4];
                float vv[4] = {v4.x, v4.y, v4.z, v4.w};
#pragma unroll
                for (int e = 0; e < 4; e++)
                    if (vv[e] < d20[KNN - 1])
                        insert20(vv[e], cb + g * 4 + e, d20, i20);
            }
        }
    }

    if (L < 16) {
        long o = (((long)b * 4 + quart) * N_PTS + (q0 + qw + L)) * KNN;
#pragma unroll
        for (int j = 0; j < KNN; j++) { knnd[o + j] = d20[j]; knni[o + j] = i20[j]; }
    }
}

// ---------------------------------------------------------------------------
// Merge the four sorted quarter-lists per query into final idx[b][i][KNN]
// (set semantics — downstream max-pool is order-invariant)
// ---------------------------------------------------------------------------
__global__ void knn_merge4(const float* __restrict__ knnd, const int* __restrict__ knni,
                           int* __restrict__ idxOut)
{
    int id = blockIdx.x * 256 + threadIdx.x;   // b*N + i
    int b = id / N_PTS, i = id % N_PTS;
    const float* dl[4]; const int* il[4];
#pragma unroll
    for (int qt = 0; qt < 4; qt++) {
        dl[qt] = knnd + (((long)b * 4 + qt) * N_PTS + i) * KNN;
        il[qt] = knni + (((long)b * 4 + qt) * N_PTS + i) * KNN;
    }
    int p[4] = {0, 0, 0, 0};
    int* o = idxOut + (long)id * KNN;
#pragma unroll
    for (int j = 0; j < KNN; j++) {
        float best = FLT_MAX; int bq = 0;
#pragma unroll
        for (int qt = 0; qt < 4; qt++) {
            float vv = (p[qt] < KNN) ? dl[qt][p[qt]] : FLT_MAX;
            if (vv < best) { best = vv; bq = qt; }
        }
        o[j] = il[bq][p[bq]];
        p[bq]++;
    }
}

// ---------------------------------------------------------------------------
__global__ void prep_xt_kernel(const float* __restrict__ x, float* __restrict__ xt)
{
    int id = blockIdx.x * 256 + threadIdx.x;    // < 4*3*4096
    int b = id / (3 * N_PTS);
    int rem = id % (3 * N_PTS);
    int c = rem / N_PTS;
    int i = rem % N_PTS;
    xt[id] = x[((long)b * N_PTS + i) * 3 + c];
}

__global__ void sqnorm_kernel(const float* __restrict__ F, float* __restrict__ xx,
                              int C, long bsF)
{
    int b = blockIdx.y;
    int j = blockIdx.x * 256 + threadIdx.x;
    const float* f = F + (long)b * bsF;
    float s = 0.f;
    for (int c = 0; c < C; c++) {
        float t = f[(long)c * N_PTS + j];
        s = fmaf(t, t, s);
    }
    xx[(long)b * N_PTS + j] = s;
}

__global__ void fold_edge_kernel(const float* __restrict__ W, const float* __restrict__ g,
                                 const float* __restrict__ bb, const float* __restrict__ m,
                                 const float* __restrict__ v,
                                 float* __restrict__ Atq, float* __restrict__ Atp,
                                 float* __restrict__ shift, int C, int cout)
{
    int id = blockIdx.x * 256 + threadIdx.x;
    if (id < C * cout) {
        int o = id % cout;
        int c = id / cout;
        float sc = g[o] * rsqrtf(v[o] + EPSB);
        float wd = W[(long)o * 2 * C + c];
        float wc = W[(long)o * 2 * C + C + c];
        Atq[id] = sc * wd;
        Atp[id] = sc * (wc - wd);
    }
    if (id < cout) {
        float sc = g[id] * rsqrtf(v[id] + EPSB);
        shift[id] = bb[id] - m[id] * sc;
    }
}

__global__ void fold_plain_kernel(const float* __restrict__ W, const float* __restrict__ g,
                                  const float* __restrict__ bb, const float* __restrict__ m,
                                  const float* __restrict__ v,
                                  float* __restrict__ Atq, float* __restrict__ shift,
                                  int C, int cout)
{
    int id = blockIdx.x * 256 + threadIdx.x;
    if (id < C * cout) {
        int o = id % cout;
        int c = id / cout;
        float sc = g[o] * rsqrtf(v[o] + EPSB);
        Atq[id] = sc * W[(long)o * C + c];
    }
    if (id < cout) {
        float sc = g[id] * rsqrtf(v[id] + EPSB);
        shift[id] = bb[id] - m[id] * sc;
    }
}

__global__ void gather_max_kernel(const float* __restrict__ q, const float* __restrict__ p,
                                  const int* __restrict__ idx, float* __restrict__ cat,
                                  int cout, int c_off)
{
    int b = blockIdx.y;
    int i = blockIdx.x * 4 + threadIdx.y;
    int tx = threadIdx.x;
    const int* ip = idx + ((long)b * N_PTS + i) * KNN;
    int js[KNN];
#pragma unroll
    for (int k = 0; k < KNN; k++) js[k] = ip[k];
    const float* qb = q + (long)b * N_PTS * cout;
    const float* pb = p + ((long)b * N_PTS + i) * cout;
    float* ob = cat + ((long)b * 512 + c_off) * N_PTS + i;
    for (int o0 = 0; o0 < cout; o0 += 64) {
        int o = o0 + tx;
        float pv = pb[o];
        float mx = -FLT_MAX;
#pragma unroll
        for (int k = 0; k < KNN; k++) {
            float val = qb[(long)js[k] * cout + o] + pv;
            val = val >= 0.f ? val : 0.2f * val;
            mx = fmaxf(mx, val);
        }
        ob[(long)o * N_PTS] = mx;
    }
}

__global__ void edge0_kernel(const float* __restrict__ xt, const int* __restrict__ idx,
                             const float* __restrict__ W0, const float* __restrict__ g0,
                             const float* __restrict__ b0, const float* __restrict__ m0,
                             const float* __restrict__ v0, float* __restrict__ cat)
{
    int b = blockIdx.y;
    int i = blockIdx.x * 4 + threadIdx.y;
    int o = threadIdx.x;
    const float* xb = xt + (long)b * 3 * N_PTS;
    float cx = xb[i], cy = xb[N_PTS + i], cz = xb[2 * N_PTS + i];
    float w[9];
#pragma unroll
    for (int c = 0; c < 9; c++) w[c] = W0[o * 9 + c];
    float sc = g0[o] * rsqrtf(v0[o] + EPSB);
    float sh = b0[o] - m0[o] * sc;
    const int* ip = idx + ((long)b * N_PTS + i) * KNN;
    float mx = -FLT_MAX;
#pragma unroll
    for (int k = 0; k < KNN; k++) {
        int j = ip[k];
        float nx = xb[j], ny = xb[N_PTS + j], nz = xb[2 * N_PTS + j];
        float dx = nx - cx, dy = ny - cy, dz = nz - cz;
        float crx = cy * nz - cz * ny;
        float cry = cz * nx - cx * nz;
        float crz = cx * ny - cy * nx;
        float y = w[0] * dx + w[1] * dy + w[2] * dz
                + w[3] * crx + w[4] * cry + w[5] * crz
                + w[6] * cx + w[7] * cy + w[8] * cz;
        y = y * sc + sh;
        y = y >= 0.f ? y : 0.2f * y;
        mx = fmaxf(mx, y);
    }
    cat[((long)b * 512 + o) * N_PTS + i] = mx;
}

__global__ void rowmax_kernel(const float* __restrict__ Y, float* __restrict__ ymax)
{
    __shared__ float red[256];
    int b = blockIdx.y, o = blockIdx.x, t = threadIdx.x;
    const float* yb = Y + ((long)b * 512 + o) * N_PTS;
    float mx = -FLT_MAX;
#pragma unroll
    for (int s = 0; s < N_PTS / 256; s++) mx = fmaxf(mx, yb[t + 256 * s]);
    red[t] = mx;
    __syncthreads();
    for (int off = 128; off > 0; off >>= 1) {
        if (t < off) red[t] = fmaxf(red[t], red[t + off]);
        __syncthreads();
    }
    if (t == 0) ymax[(long)b * 512 + o] = red[0];
}

__global__ void head_kernel(const float* __restrict__ ymax, const float* __restrict__ We,
                            const float* __restrict__ Wh, const float* __restrict__ bh,
                            float* __restrict__ out)
{
    __shared__ float emb[128];
    __shared__ float yv[512];
    int b = blockIdx.x, t = threadIdx.x;
    for (int s = t; s < 512; s += 128) yv[s] = ymax[(long)b * 512 + s];
    __syncthreads();
    float acc = 0.f;
    for (int c = 0; c < 512; c++) acc = fmaf(yv[c], We[(long)t * 512 + c], acc);
    emb[t] = acc;
    __syncthreads();
    float acc2 = bh[t];
    for (int ff = 0; ff < 128; ff++) acc2 = fmaf(emb[ff], Wh[(long)t * 128 + ff], acc2);
    out[(long)b * 128 + t] = acc2;
}

// ---------------------------------------------------------------------------
extern "C" void kernel_launch(void* const* d_in, const int* in_sizes, int n_in,
                              void* d_out, int out_size, void* d_ws, size_t ws_size,
                              hipStream_t stream)
{
    const float* x = (const float*)d_in[0];
    const float *W[5], *g[5], *bb[5], *m[5], *v[5];
    for (int li = 0; li < 5; li++) {
        W[li]  = (const float*)d_in[1 + li * 5 + 0];
        g[li]  = (const float*)d_in[1 + li * 5 + 1];
        bb[li] = (const float*)d_in[1 + li * 5 + 2];
        m[li]  = (const float*)d_in[1 + li * 5 + 3];
        v[li]  = (const float*)d_in[1 + li * 5 + 4];
    }
    const float* We = (const float*)d_in[26];
    const float* Wh = (const float*)d_in[27];
    const float* bh = (const float*)d_in[28];
    float* out = (float*)d_out;

    // workspace carve (floats)
    float* ws   = (float*)d_ws;
    float* cat  = ws;                                   // 8,388,608 (B,512,N)
    float* qbuf = cat + (long)8388608;                  // 8,388,608 (q + stage4 Y)
    float* pbuf = qbuf + (long)8388608;                 // 4,194,304
    // knn scratch lives inside pbuf (disjoint lifetime with p-values)
    float* knnd = pbuf;                                 // 1,310,720
    int*   knni = (int*)(pbuf + 1310720);               // 1,310,720
    int*   idxb = (int*)(pbuf + 4194304);               // 327,680 ints
    float* xt   = (float*)(idxb + 327680);              // 49,152
    float* xx   = xt + 49152;                           // 16,384
    float* Atq  = xx + 16384;                           // 262,144
    float* Atp  = Atq + 262144;                         // 262,144
    float* shf  = Atp + 262144;                         // 512
    float* ymax = shf + 512;                            // 2,048
    // bf16 hi/lo feature arrays live in qbuf (disjoint lifetime: written by
    // to_bf16_tr + read by fused_knn_mfma BEFORE the q-GEMM overwrites qbuf)
    unsigned short* Ghi = (unsigned short*)qbuf;        // 2,097,152 shorts
    unsigned short* Glo = Ghi + (long)N_PTS * 128 * NB; // 2,097,152 shorts

    // ---- prep ----
    prep_xt_kernel<<<dim3(192), dim3(256), 0, stream>>>(x, xt);

    // ---- stage 0: knn on coords (C=3, K padded to 32) ----
    sqnorm_kernel<<<dim3(16, NB), dim3(256), 0, stream>>>(xt, xx, 3, (long)3 * N_PTS);
    to_bf16_tr<<<dim3(64, NB), dim3(256), 0, stream>>>(
        xt, (long)3 * N_PTS, 3, 32, Ghi, Glo);
    fused_knn_mfma<32><<<dim3(64, 4, NB), dim3(256), 0, stream>>>(
        Ghi, Glo, xx, knnd, knni);
    knn_merge4<<<dim3(64), dim3(256), 0, stream>>>(knnd, knni, idxb);
    edge0_kernel<<<dim3(N_PTS / 4, NB), dim3(64, 4), 0, stream>>>(
        xt, idxb, W[0], g[0], bb[0], m[0], v[0], cat);

    // ---- stages 1..3 ----
    const int Cs_[3]   = {64, 64, 128};
    const int co_[3]   = {64, 128, 256};
    const int inO_[3]  = {0, 64, 128};
    const int outO_[3] = {64, 128, 256};
    for (int s = 0; s < 3; s++) {
        int C = Cs_[s], cout = co_[s];
        const float* F = cat + (long)inO_[s] * N_PTS;   // batch stride 512*N
        sqnorm_kernel<<<dim3(16, NB), dim3(256), 0, stream>>>(F, xx, C, (long)512 * N_PTS);
        to_bf16_tr<<<dim3(64, NB), dim3(256), 0, stream>>>(
            F, (long)512 * N_PTS, C, C, Ghi, Glo);
        if (C == 64)
            fused_knn_mfma<64><<<dim3(64, 4, NB), dim3(256), 0, stream>>>(
                Ghi, Glo, xx, knnd, knni);
        else
            fused_knn_mfma<128><<<dim3(64, 4, NB), dim3(256), 0, stream>>>(
                Ghi, Glo, xx, knnd, knni);
        knn_merge4<<<dim3(64), dim3(256), 0, stream>>>(knnd, knni, idxb);

        int li = s + 1;
        fold_edge_kernel<<<dim3((C * cout + 255) / 256), dim3(256), 0, stream>>>(
            W[li], g[li], bb[li], m[li], v[li], Atq, Atp, shf, C, cout);
        // q: Out[j][o] point-major (overwrites Ghi/Glo region — knn done)
        gemm_kmajor<<<dim3(N_PTS / 64, cout / 64, NB), dim3(256), 0, stream>>>(
            F, Atq, qbuf, nullptr,
            C, N_PTS, cout, cout, (long)512 * N_PTS, 0, (long)N_PTS * cout, 0);
        // p: Out[i][o] + shift[o]
        gemm_kmajor<<<dim3(N_PTS / 64, cout / 64, NB), dim3(256), 0, stream>>>(
            F, Atp, pbuf, shf,
            C, N_PTS, cout, cout, (long)512 * N_PTS, 0, (long)N_PTS * cout, 1);
        gather_max_kernel<<<dim3(N_PTS / 4, NB), dim3(64, 4), 0, stream>>>(
            qbuf, pbuf, idxb, cat, cout, outO_[s]);
    }

    // ---- stage 4: pointwise conv + bn + lrelu, channel-major out ----
    fold_plain_kernel<<<dim3((512 * 512 + 255) / 256), dim3(256), 0, stream>>>(
        W[4], g[4], bb[4], m[4], v[4], Atq, shf, 512, 512);
    gemm_kmajor<<<dim3(512 / 64, N_PTS / 64, NB), dim3(256), 0, stream>>>(
        Atq, cat, qbuf, shf,
        512, 512, N_PTS, N_PTS, 0, (long)512 * N_PTS, (long)512 * N_PTS, 2);

    // ---- global max + head ----
    rowmax_kernel<<<dim3(512, NB), dim3(256), 0, stream>>>(qbuf, ymax);
    head_kernel<<<dim3(NB), dim3(128), 0, stream>>>(ymax, We, Wh, bh, out);
}

// Round 8
// 1680.800 us; speedup vs baseline: 1.4687x; 1.4687x over previous
//
#include <hip/hip_runtime.h>
#include <cfloat>

#define N_PTS 4096
#define NB    4
#define KNN   20
#define EPSB  1e-5f

#define BT 64
#define KT 16

typedef short s8v __attribute__((ext_vector_type(8)));
typedef float f4v __attribute__((ext_vector_type(4)));

// ---------------------------------------------------------------------------
// Generic K-major GEMM: Out[row][col] = sum_k Mr[k][row] * Mc[k][col]
// mode 0: plain  | mode 1: +aux1[col] | mode 2: lrelu(val+aux1[row])
// ---------------------------------------------------------------------------
__global__ __launch_bounds__(256)
void gemm_kmajor(const float* __restrict__ Mr, const float* __restrict__ Mc,
                 float* __restrict__ Out,
                 const float* __restrict__ aux1,
                 int K, int ldr, int ldc, int ldo,
                 long bsR, long bsC, long bsO,
                 int mode)
{
    __shared__ float Rs[KT][BT];
    __shared__ float Cs[KT][BT];
    int bz = blockIdx.z;
    const float* mr = Mr + bz * bsR;
    const float* mc = Mc + bz * bsC;
    float* outp = Out + bz * bsO;
    int row0 = blockIdx.x * BT;
    int col0 = blockIdx.y * BT;
    int tid = threadIdx.x;
    int tx = tid & 15, ty = tid >> 4;

    float acc[4][4];
#pragma unroll
    for (int r = 0; r < 4; r++)
#pragma unroll
        for (int c = 0; c < 4; c++) acc[r][c] = 0.f;

    for (int k0 = 0; k0 < K; k0 += KT) {
#pragma unroll
        for (int l = 0; l < (KT * BT) / 256; l++) {
            int e = l * 256 + tid;
            int kk = e >> 6, r = e & 63;
            int kg = k0 + kk;
            float rv = 0.f, cv = 0.f;
            if (kg < K) {
                rv = mr[(long)kg * ldr + row0 + r];
                cv = mc[(long)kg * ldc + col0 + r];
            }
            Rs[kk][r] = rv;
            Cs[kk][r] = cv;
        }
        __syncthreads();
#pragma unroll
        for (int kk = 0; kk < KT; kk++) {
            float rv[4], cv[4];
#pragma unroll
            for (int e = 0; e < 4; e++) rv[e] = Rs[kk][ty * 4 + e];
#pragma unroll
            for (int e = 0; e < 4; e++) cv[e] = Cs[kk][tx * 4 + e];
#pragma unroll
            for (int r = 0; r < 4; r++)
#pragma unroll
                for (int c = 0; c < 4; c++)
                    acc[r][c] = fmaf(rv[r], cv[c], acc[r][c]);
        }
        __syncthreads();
    }

    int orow = row0 + ty * 4;
    int ocol = col0 + tx * 4;
#pragma unroll
    for (int r = 0; r < 4; r++) {
        float vv[4];
#pragma unroll
        for (int c = 0; c < 4; c++) {
            float val = acc[r][c];
            if (mode == 1) {
                val += aux1[ocol + c];
            } else if (mode == 2) {
                val += aux1[orow + r];
                val = val >= 0.f ? val : 0.2f * val;
            }
            vv[c] = val;
        }
        float4 v4;
        v4.x = vv[0]; v4.y = vv[1]; v4.z = vv[2]; v4.w = vv[3];
        *(float4*)(outp + (long)(orow + r) * ldo + ocol) = v4;
    }
}

// ---------------------------------------------------------------------------
// Sorted top-20 register insert (strict <, stable: earlier/lower index wins).
// ---------------------------------------------------------------------------
__device__ __forceinline__ void insert20(float dv, int ci,
                                         float (&d20)[KNN], int (&i20)[KNN])
{
#pragma unroll
    for (int j2 = KNN - 1; j2 >= 1; j2--) {
        float pm = d20[j2 - 1]; int im = i20[j2 - 1];
        bool sh  = dv < pm;
        bool ins = (!sh) && (dv < d20[j2]);
        d20[j2] = sh ? pm : (ins ? dv : d20[j2]);
        i20[j2] = sh ? im : (ins ? ci : i20[j2]);
    }
    if (dv < d20[0]) { d20[0] = dv; i20[0] = ci; }
}

// ---------------------------------------------------------------------------
// fp32 -> bf16 hi/lo split, transposed to [b][point][k] (MFMA fragment order).
// grid (N/64, B), block 256 (64 points x 4 k-octets). k >= C zero-filled.
// ---------------------------------------------------------------------------
__global__ __launch_bounds__(256)
void to_bf16_tr(const float* __restrict__ F, long bsF, int C, int KDP,
                unsigned short* __restrict__ Ghi, unsigned short* __restrict__ Glo)
{
    int b = blockIdx.y;
    int n = blockIdx.x * 64 + (threadIdx.x & 63);
    int kq = threadIdx.x >> 6;
    const float* Fb = F + (long)b * bsF;
    for (int k0 = kq * 8; k0 < KDP; k0 += 32) {
        s8v hv, lv;
#pragma unroll
        for (int i = 0; i < 8; i++) {
            int k = k0 + i;
            float x = (k < C) ? Fb[(long)k * N_PTS + n] : 0.f;
            unsigned u = __builtin_bit_cast(unsigned, x);
            unsigned hb = (u + 0x7fffu + ((u >> 16) & 1u)) >> 16;
            float hf = __builtin_bit_cast(float, hb << 16);
            float res = x - hf;
            unsigned u2 = __builtin_bit_cast(unsigned, res);
            unsigned lb = (u2 + 0x7fffu + ((u2 >> 16) & 1u)) >> 16;
            hv[i] = (short)hb;
            lv[i] = (short)lb;
        }
        long o = ((long)b * N_PTS + n) * KDP + k0;
        *(s8v*)&Ghi[o] = hv;
        *(s8v*)&Glo[o] = lv;
    }
}

// ---------------------------------------------------------------------------
// MFMA fused distance + top-20, v2: in-register selection.
// grid (N/64, 4 quarters, B), block 256 (4 waves, one barrier pair total).
// Wave w: 16 queries (q0+w*16..+15) x 1024 quarter-candidates.
// MFMA roles: A = candidate tile (m=candidate), B = wave queries (n=query).
// C/D layout -> lane L holds query n=L&15 (FIXED) and candidates
// quad*4+r (quad=L>>4) per accumulator register. Selection therefore runs
// entirely on registers: each lane keeps the top-20 of its 1/4 candidate
// slice (global top-20 is a subset of the union of slice top-20s).
// Epilogue: per-wave LDS merge of the 4 quad-lane lists per query
// (LDS = exactly 40,960 B -> 4 blocks/CU).
// Inner products: 3x mfma_f32_16x16x32_bf16 per k-step (hh + h.lo + lo.h),
// exact fp32 xx terms added afterwards.
// Out: knnd/knni [b][quart][N][KNN] sorted ascending.
// ---------------------------------------------------------------------------
template<int KDP>
__global__ __launch_bounds__(256)
void fused_knn_mfma2(const unsigned short* __restrict__ Ghi,
                     const unsigned short* __restrict__ Glo,
                     const float* __restrict__ xx,
                     float* __restrict__ knnd, int* __restrict__ knni)
{
    constexpr int KS = KDP / 32;
    __shared__ float md[4][16][4][KNN];   // 20,480 B
    __shared__ int   mi[4][16][4][KNN];   // 20,480 B  (total 40,960)

    int tid = threadIdx.x;
    int w = tid >> 6, L = tid & 63;
    int n = L & 15;            // this lane's fixed query slot
    int quad = L >> 4;
    int b = blockIdx.z, quart = blockIdx.y;
    int q0 = blockIdx.x * 64, qw = w * 16;
    const unsigned short* Gh = Ghi + (long)b * N_PTS * KDP;
    const unsigned short* Gl = Glo + (long)b * N_PTS * KDP;
    const float* xxb = xx + (long)b * N_PTS;

    // B fragments: wave's 16 queries, hi+lo, all k-steps (persistent)
    s8v qhi[KS], qlo[KS];
    long qbase = (long)(q0 + qw + n) * KDP + quad * 8;
#pragma unroll
    for (int ks = 0; ks < KS; ks++) {
        qhi[ks] = *(const s8v*)&Gh[qbase + ks * 32];
        qlo[ks] = *(const s8v*)&Gl[qbase + ks * 32];
    }
    float xq = xxb[q0 + qw + n];

    float d20[KNN]; int i20[KNN];
#pragma unroll
    for (int j = 0; j < KNN; j++) { d20[j] = FLT_MAX; i20[j] = 0; }

    for (int t = 0; t < 64; t++) {
        int n0 = quart * 1024 + t * 16;
        f4v acc = {0.f, 0.f, 0.f, 0.f};
        long cbase = (long)(n0 + n) * KDP + quad * 8;  // lane provides cand row n0+n
#pragma unroll
        for (int ks = 0; ks < KS; ks++) {
            s8v chi = *(const s8v*)&Gh[cbase + ks * 32];
            s8v clo = *(const s8v*)&Gl[cbase + ks * 32];
            acc = __builtin_amdgcn_mfma_f32_16x16x32_bf16(chi, qhi[ks], acc, 0, 0, 0);
            acc = __builtin_amdgcn_mfma_f32_16x16x32_bf16(chi, qlo[ks], acc, 0, 0, 0);
            acc = __builtin_amdgcn_mfma_f32_16x16x32_bf16(clo, qhi[ks], acc, 0, 0, 0);
        }
        float4 xc4 = *(const float4*)&xxb[n0 + quad * 4];
        float xcv[4] = {xc4.x, xc4.y, xc4.z, xc4.w};
#pragma unroll
        for (int r = 0; r < 4; r++) {
            float d = xq + xcv[r] - 2.f * acc[r];
            if (d < d20[KNN - 1])
                insert20(d, n0 + quad * 4 + r, d20, i20);
        }
    }

    // publish per-lane lists, then 16 owner lanes merge 4 quad-slices/query
#pragma unroll
    for (int j = 0; j < KNN; j++) {
        md[w][n][quad][j] = d20[j];
        mi[w][n][quad][j] = i20[j];
    }
    __syncthreads();
    if (L < 16) {
        int p[4] = {0, 0, 0, 0};
        long o = (((long)b * 4 + quart) * N_PTS + (q0 + qw + L)) * KNN;
#pragma unroll
        for (int j = 0; j < KNN; j++) {
            float best = FLT_MAX; int bi = 0x7fffffff; int bq = 0;
#pragma unroll
            for (int qd = 0; qd < 4; qd++) {
                float dv = md[w][L][qd][p[qd]];
                int   ci = mi[w][L][qd][p[qd]];
                if (dv < best || (dv == best && ci < bi)) { best = dv; bi = ci; bq = qd; }
            }
            knnd[o + j] = best;
            knni[o + j] = bi;
            p[bq]++;
        }
    }
}

// ---------------------------------------------------------------------------
// Merge the four sorted quarter-lists per query into final idx[b][i][KNN]
// (set semantics — downstream max-pool is order-invariant)
// ---------------------------------------------------------------------------
__global__ void knn_merge4(const float* __restrict__ knnd, const int* __restrict__ knni,
                           int* __restrict__ idxOut)
{
    int id = blockIdx.x * 256 + threadIdx.x;   // b*N + i
    int b = id / N_PTS, i = id % N_PTS;
    const float* dl[4]; const int* il[4];
#pragma unroll
    for (int qt = 0; qt < 4; qt++) {
        dl[qt] = knnd + (((long)b * 4 + qt) * N_PTS + i) * KNN;
        il[qt] = knni + (((long)b * 4 + qt) * N_PTS + i) * KNN;
    }
    int p[4] = {0, 0, 0, 0};
    int* o = idxOut + (long)id * KNN;
#pragma unroll
    for (int j = 0; j < KNN; j++) {
        float best = FLT_MAX; int bq = 0;
#pragma unroll
        for (int qt = 0; qt < 4; qt++) {
            float vv = (p[qt] < KNN) ? dl[qt][p[qt]] : FLT_MAX;
            if (vv < best) { best = vv; bq = qt; }
        }
        o[j] = il[bq][p[bq]];
        p[bq]++;
    }
}

// ---------------------------------------------------------------------------
__global__ void prep_xt_kernel(const float* __restrict__ x, float* __restrict__ xt)
{
    int id = blockIdx.x * 256 + threadIdx.x;    // < 4*3*4096
    int b = id / (3 * N_PTS);
    int rem = id % (3 * N_PTS);
    int c = rem / N_PTS;
    int i = rem % N_PTS;
    xt[id] = x[((long)b * N_PTS + i) * 3 + c];
}

__global__ void sqnorm_kernel(const float* __restrict__ F, float* __restrict__ xx,
                              int C, long bsF)
{
    int b = blockIdx.y;
    int j = blockIdx.x * 256 + threadIdx.x;
    const float* f = F + (long)b * bsF;
    float s = 0.f;
    for (int c = 0; c < C; c++) {
        float t = f[(long)c * N_PTS + j];
        s = fmaf(t, t, s);
    }
    xx[(long)b * N_PTS + j] = s;
}

__global__ void fold_edge_kernel(const float* __restrict__ W, const float* __restrict__ g,
                                 const float* __restrict__ bb, const float* __restrict__ m,
                                 const float* __restrict__ v,
                                 float* __restrict__ Atq, float* __restrict__ Atp,
                                 float* __restrict__ shift, int C, int cout)
{
    int id = blockIdx.x * 256 + threadIdx.x;
    if (id < C * cout) {
        int o = id % cout;
        int c = id / cout;
        float sc = g[o] * rsqrtf(v[o] + EPSB);
        float wd = W[(long)o * 2 * C + c];
        float wc = W[(long)o * 2 * C + C + c];
        Atq[id] = sc * wd;
        Atp[id] = sc * (wc - wd);
    }
    if (id < cout) {
        float sc = g[id] * rsqrtf(v[id] + EPSB);
        shift[id] = bb[id] - m[id] * sc;
    }
}

__global__ void fold_plain_kernel(const float* __restrict__ W, const float* __restrict__ g,
                                  const float* __restrict__ bb, const float* __restrict__ m,
                                  const float* __restrict__ v,
                                  float* __restrict__ Atq, float* __restrict__ shift,
                                  int C, int cout)
{
    int id = blockIdx.x * 256 + threadIdx.x;
    if (id < C * cout) {
        int o = id % cout;
        int c = id / cout;
        float sc = g[o] * rsqrtf(v[o] + EPSB);
        Atq[id] = sc * W[(long)o * C + c];
    }
    if (id < cout) {
        float sc = g[id] * rsqrtf(v[id] + EPSB);
        shift[id] = bb[id] - m[id] * sc;
    }
}

__global__ void gather_max_kernel(const float* __restrict__ q, const float* __restrict__ p,
                                  const int* __restrict__ idx, float* __restrict__ cat,
                                  int cout, int c_off)
{
    int b = blockIdx.y;
    int i = blockIdx.x * 4 + threadIdx.y;
    int tx = threadIdx.x;
    const int* ip = idx + ((long)b * N_PTS + i) * KNN;
    int js[KNN];
#pragma unroll
    for (int k = 0; k < KNN; k++) js[k] = ip[k];
    const float* qb = q + (long)b * N_PTS * cout;
    const float* pb = p + ((long)b * N_PTS + i) * cout;
    float* ob = cat + ((long)b * 512 + c_off) * N_PTS + i;
    for (int o0 = 0; o0 < cout; o0 += 64) {
        int o = o0 + tx;
        float pv = pb[o];
        float mx = -FLT_MAX;
#pragma unroll
        for (int k = 0; k < KNN; k++) {
            float val = qb[(long)js[k] * cout + o] + pv;
            val = val >= 0.f ? val : 0.2f * val;
            mx = fmaxf(mx, val);
        }
        ob[(long)o * N_PTS] = mx;
    }
}

__global__ void edge0_kernel(const float* __restrict__ xt, const int* __restrict__ idx,
                             const float* __restrict__ W0, const float* __restrict__ g0,
                             const float* __restrict__ b0, const float* __restrict__ m0,
                             const float* __restrict__ v0, float* __restrict__ cat)
{
    int b = blockIdx.y;
    int i = blockIdx.x * 4 + threadIdx.y;
    int o = threadIdx.x;
    const float* xb = xt + (long)b * 3 * N_PTS;
    float cx = xb[i], cy = xb[N_PTS + i], cz = xb[2 * N_PTS + i];
    float w[9];
#pragma unroll
    for (int c = 0; c < 9; c++) w[c] = W0[o * 9 + c];
    float sc = g0[o] * rsqrtf(v0[o] + EPSB);
    float sh = b0[o] - m0[o] * sc;
    const int* ip = idx + ((long)b * N_PTS + i) * KNN;
    float mx = -FLT_MAX;
#pragma unroll
    for (int k = 0; k < KNN; k++) {
        int j = ip[k];
        float nx = xb[j], ny = xb[N_PTS + j], nz = xb[2 * N_PTS + j];
        float dx = nx - cx, dy = ny - cy, dz = nz - cz;
        float crx = cy * nz - cz * ny;
        float cry = cz * nx - cx * nz;
        float crz = cx * ny - cy * nx;
        float y = w[0] * dx + w[1] * dy + w[2] * dz
                + w[3] * crx + w[4] * cry + w[5] * crz
                + w[6] * cx + w[7] * cy + w[8] * cz;
        y = y * sc + sh;
        y = y >= 0.f ? y : 0.2f * y;
        mx = fmaxf(mx, y);
    }
    cat[((long)b * 512 + o) * N_PTS + i] = mx;
}

__global__ void rowmax_kernel(const float* __restrict__ Y, float* __restrict__ ymax)
{
    __shared__ float red[256];
    int b = blockIdx.y, o = blockIdx.x, t = threadIdx.x;
    const float* yb = Y + ((long)b * 512 + o) * N_PTS;
    float mx = -FLT_MAX;
#pragma unroll
    for (int s = 0; s < N_PTS / 256; s++) mx = fmaxf(mx, yb[t + 256 * s]);
    red[t] = mx;
    __syncthreads();
    for (int off = 128; off > 0; off >>= 1) {
        if (t < off) red[t] = fmaxf(red[t], red[t + off]);
        __syncthreads();
    }
    if (t == 0) ymax[(long)b * 512 + o] = red[0];
}

__global__ void head_kernel(const float* __restrict__ ymax, const float* __restrict__ We,
                            const float* __restrict__ Wh, const float* __restrict__ bh,
                            float* __restrict__ out)
{
    __shared__ float emb[128];
    __shared__ float yv[512];
    int b = blockIdx.x, t = threadIdx.x;
    for (int s = t; s < 512; s += 128) yv[s] = ymax[(long)b * 512 + s];
    __syncthreads();
    float acc = 0.f;
    for (int c = 0; c < 512; c++) acc = fmaf(yv[c], We[(long)t * 512 + c], acc);
    emb[t] = acc;
    __syncthreads();
    float acc2 = bh[t];
    for (int ff = 0; ff < 128; ff++) acc2 = fmaf(emb[ff], Wh[(long)t * 128 + ff], acc2);
    out[(long)b * 128 + t] = acc2;
}

// ---------------------------------------------------------------------------
extern "C" void kernel_launch(void* const* d_in, const int* in_sizes, int n_in,
                              void* d_out, int out_size, void* d_ws, size_t ws_size,
                              hipStream_t stream)
{
    const float* x = (const float*)d_in[0];
    const float *W[5], *g[5], *bb[5], *m[5], *v[5];
    for (int li = 0; li < 5; li++) {
        W[li]  = (const float*)d_in[1 + li * 5 + 0];
        g[li]  = (const float*)d_in[1 + li * 5 + 1];
        bb[li] = (const float*)d_in[1 + li * 5 + 2];
        m[li]  = (const float*)d_in[1 + li * 5 + 3];
        v[li]  = (const float*)d_in[1 + li * 5 + 4];
    }
    const float* We = (const float*)d_in[26];
    const float* Wh = (const float*)d_in[27];
    const float* bh = (const float*)d_in[28];
    float* out = (float*)d_out;

    // workspace carve (floats)
    float* ws   = (float*)d_ws;
    float* cat  = ws;                                   // 8,388,608 (B,512,N)
    float* qbuf = cat + (long)8388608;                  // 8,388,608 (q + stage4 Y)
    float* pbuf = qbuf + (long)8388608;                 // 4,194,304
    // knn scratch lives inside pbuf (disjoint lifetime with p-values)
    float* knnd = pbuf;                                 // 1,310,720
    int*   knni = (int*)(pbuf + 1310720);               // 1,310,720
    int*   idxb = (int*)(pbuf + 4194304);               // 327,680 ints
    float* xt   = (float*)(idxb + 327680);              // 49,152
    float* xx   = xt + 49152;                           // 16,384
    float* Atq  = xx + 16384;                           // 262,144
    float* Atp  = Atq + 262144;                         // 262,144
    float* shf  = Atp + 262144;                         // 512
    float* ymax = shf + 512;                            // 2,048
    // bf16 hi/lo feature arrays live in qbuf (disjoint lifetime: written by
    // to_bf16_tr + read by fused_knn_mfma2 BEFORE the q-GEMM overwrites qbuf)
    unsigned short* Ghi = (unsigned short*)qbuf;        // 2,097,152 shorts
    unsigned short* Glo = Ghi + (long)N_PTS * 128 * NB; // 2,097,152 shorts

    // ---- prep ----
    prep_xt_kernel<<<dim3(192), dim3(256), 0, stream>>>(x, xt);

    // ---- stage 0: knn on coords (C=3, K padded to 32) ----
    sqnorm_kernel<<<dim3(16, NB), dim3(256), 0, stream>>>(xt, xx, 3, (long)3 * N_PTS);
    to_bf16_tr<<<dim3(64, NB), dim3(256), 0, stream>>>(
        xt, (long)3 * N_PTS, 3, 32, Ghi, Glo);
    fused_knn_mfma2<32><<<dim3(64, 4, NB), dim3(256), 0, stream>>>(
        Ghi, Glo, xx, knnd, knni);
    knn_merge4<<<dim3(64), dim3(256), 0, stream>>>(knnd, knni, idxb);
    edge0_kernel<<<dim3(N_PTS / 4, NB), dim3(64, 4), 0, stream>>>(
        xt, idxb, W[0], g[0], bb[0], m[0], v[0], cat);

    // ---- stages 1..3 ----
    const int Cs_[3]   = {64, 64, 128};
    const int co_[3]   = {64, 128, 256};
    const int inO_[3]  = {0, 64, 128};
    const int outO_[3] = {64, 128, 256};
    for (int s = 0; s < 3; s++) {
        int C = Cs_[s], cout = co_[s];
        const float* F = cat + (long)inO_[s] * N_PTS;   // batch stride 512*N
        sqnorm_kernel<<<dim3(16, NB), dim3(256), 0, stream>>>(F, xx, C, (long)512 * N_PTS);
        to_bf16_tr<<<dim3(64, NB), dim3(256), 0, stream>>>(
            F, (long)512 * N_PTS, C, C, Ghi, Glo);
        if (C == 64)
            fused_knn_mfma2<64><<<dim3(64, 4, NB), dim3(256), 0, stream>>>(
                Ghi, Glo, xx, knnd, knni);
        else
            fused_knn_mfma2<128><<<dim3(64, 4, NB), dim3(256), 0, stream>>>(
                Ghi, Glo, xx, knnd, knni);
        knn_merge4<<<dim3(64), dim3(256), 0, stream>>>(knnd, knni, idxb);

        int li = s + 1;
        fold_edge_kernel<<<dim3((C * cout + 255) / 256), dim3(256), 0, stream>>>(
            W[li], g[li], bb[li], m[li], v[li], Atq, Atp, shf, C, cout);
        // q: Out[j][o] point-major (overwrites Ghi/Glo region — knn done)
        gemm_kmajor<<<dim3(N_PTS / 64, cout / 64, NB), dim3(256), 0, stream>>>(
            F, Atq, qbuf, nullptr,
            C, N_PTS, cout, cout, (long)512 * N_PTS, 0, (long)N_PTS * cout, 0);
        // p: Out[i][o] + shift[o]
        gemm_kmajor<<<dim3(N_PTS / 64, cout / 64, NB), dim3(256), 0, stream>>>(
            F, Atp, pbuf, shf,
            C, N_PTS, cout, cout, (long)512 * N_PTS, 0, (long)N_PTS * cout, 1);
        gather_max_kernel<<<dim3(N_PTS / 4, NB), dim3(64, 4), 0, stream>>>(
            qbuf, pbuf, idxb, cat, cout, outO_[s]);
    }

    // ---- stage 4: pointwise conv + bn + lrelu, channel-major out ----
    fold_plain_kernel<<<dim3((512 * 512 + 255) / 256), dim3(256), 0, stream>>>(
        W[4], g[4], bb[4], m[4], v[4], Atq, shf, 512, 512);
    gemm_kmajor<<<dim3(512 / 64, N_PTS / 64, NB), dim3(256), 0, stream>>>(
        Atq, cat, qbuf, shf,
        512, 512, N_PTS, N_PTS, 0, (long)512 * N_PTS, (long)512 * N_PTS, 2);

    // ---- global max + head ----
    rowmax_kernel<<<dim3(512, NB), dim3(256), 0, stream>>>(qbuf, ymax);
    head_kernel<<<dim3(NB), dim3(128), 0, stream>>>(ymax, We, Wh, bh, out);
}

// Round 9
// 1652.992 us; speedup vs baseline: 1.4934x; 1.0168x over previous
//
#include <hip/hip_runtime.h>
#include <cfloat>

#define N_PTS 4096
#define NB    4
#define KNN   20
#define EPSB  1e-5f
#define NSL   8          // knn candidate slices per batch-row

typedef short s8v __attribute__((ext_vector_type(8)));
typedef float f4v __attribute__((ext_vector_type(4)));

// ---------------------------------------------------------------------------
// bf16 hi/lo split (round-to-nearest-even both halves)
// ---------------------------------------------------------------------------
__device__ __forceinline__ void bf16split(float x, unsigned short* h, unsigned short* l)
{
    unsigned u = __builtin_bit_cast(unsigned, x);
    unsigned hb = (u + 0x7fffu + ((u >> 16) & 1u)) >> 16;
    float hf = __builtin_bit_cast(float, hb << 16);
    float res = x - hf;
    unsigned u2 = __builtin_bit_cast(unsigned, res);
    unsigned lb = (u2 + 0x7fffu + ((u2 >> 16) & 1u)) >> 16;
    *h = (unsigned short)hb;
    *l = (unsigned short)lb;
}

// ---------------------------------------------------------------------------
// Sorted top-20 register insert (strict <, stable: earlier/lower index wins).
// ---------------------------------------------------------------------------
__device__ __forceinline__ void insert20(float dv, int ci,
                                         float (&d20)[KNN], int (&i20)[KNN])
{
#pragma unroll
    for (int j2 = KNN - 1; j2 >= 1; j2--) {
        float pm = d20[j2 - 1]; int im = i20[j2 - 1];
        bool sh  = dv < pm;
        bool ins = (!sh) && (dv < d20[j2]);
        d20[j2] = sh ? pm : (ins ? dv : d20[j2]);
        i20[j2] = sh ? im : (ins ? ci : i20[j2]);
    }
    if (dv < d20[0]) { d20[0] = dv; i20[0] = ci; }
}

// ---------------------------------------------------------------------------
// fp32 -> bf16 hi/lo split, transposed to [b][point][k] (MFMA fragment order).
// grid (N/64, B), block 256 (64 points x 4 k-octets). k >= C zero-filled.
// ---------------------------------------------------------------------------
__global__ __launch_bounds__(256)
void to_bf16_tr(const float* __restrict__ F, long bsF, int C, int KDP,
                unsigned short* __restrict__ Ghi, unsigned short* __restrict__ Glo)
{
    int b = blockIdx.y;
    int n = blockIdx.x * 64 + (threadIdx.x & 63);
    int kq = threadIdx.x >> 6;
    const float* Fb = F + (long)b * bsF;
    for (int k0 = kq * 8; k0 < KDP; k0 += 32) {
        s8v hv, lv;
#pragma unroll
        for (int i = 0; i < 8; i++) {
            int k = k0 + i;
            float x = (k < C) ? Fb[(long)k * N_PTS + n] : 0.f;
            unsigned short h, l;
            bf16split(x, &h, &l);
            hv[i] = (short)h;
            lv[i] = (short)l;
        }
        long o = ((long)b * N_PTS + n) * KDP + k0;
        *(s8v*)&Ghi[o] = hv;
        *(s8v*)&Glo[o] = lv;
    }
}

// ---------------------------------------------------------------------------
// MFMA fused distance + top-20, in-register selection (8 slices).
// grid (N/64, NSL, B), block 256 (4 waves, one barrier pair total).
// Wave w: 16 queries x 512 slice-candidates. Lane L: fixed query n=L&15,
// candidates quad*4+r per acc register -> selection on registers; per-lane
// slice = 128 candidates. Epilogue: per-wave LDS merge of 4 quad lists.
// ---------------------------------------------------------------------------
template<int KDP>
__global__ __launch_bounds__(256)
void fused_knn_mfma2(const unsigned short* __restrict__ Ghi,
                     const unsigned short* __restrict__ Glo,
                     const float* __restrict__ xx,
                     float* __restrict__ knnd, int* __restrict__ knni)
{
    constexpr int KS = KDP / 32;
    __shared__ float md[4][16][4][KNN];
    __shared__ int   mi[4][16][4][KNN];

    int tid = threadIdx.x;
    int w = tid >> 6, L = tid & 63;
    int n = L & 15;
    int quad = L >> 4;
    int b = blockIdx.z, slice = blockIdx.y;
    int q0 = blockIdx.x * 64, qw = w * 16;
    const unsigned short* Gh = Ghi + (long)b * N_PTS * KDP;
    const unsigned short* Gl = Glo + (long)b * N_PTS * KDP;
    const float* xxb = xx + (long)b * N_PTS;

    s8v qhi[KS], qlo[KS];
    long qbase = (long)(q0 + qw + n) * KDP + quad * 8;
#pragma unroll
    for (int ks = 0; ks < KS; ks++) {
        qhi[ks] = *(const s8v*)&Gh[qbase + ks * 32];
        qlo[ks] = *(const s8v*)&Gl[qbase + ks * 32];
    }
    float xq = xxb[q0 + qw + n];

    float d20[KNN]; int i20[KNN];
#pragma unroll
    for (int j = 0; j < KNN; j++) { d20[j] = FLT_MAX; i20[j] = 0; }

    for (int t = 0; t < 32; t++) {
        int n0 = slice * 512 + t * 16;
        f4v acc = {0.f, 0.f, 0.f, 0.f};
        long cbase = (long)(n0 + n) * KDP + quad * 8;
#pragma unroll
        for (int ks = 0; ks < KS; ks++) {
            s8v chi = *(const s8v*)&Gh[cbase + ks * 32];
            s8v clo = *(const s8v*)&Gl[cbase + ks * 32];
            acc = __builtin_amdgcn_mfma_f32_16x16x32_bf16(chi, qhi[ks], acc, 0, 0, 0);
            acc = __builtin_amdgcn_mfma_f32_16x16x32_bf16(chi, qlo[ks], acc, 0, 0, 0);
            acc = __builtin_amdgcn_mfma_f32_16x16x32_bf16(clo, qhi[ks], acc, 0, 0, 0);
        }
        float4 xc4 = *(const float4*)&xxb[n0 + quad * 4];
        float xcv[4] = {xc4.x, xc4.y, xc4.z, xc4.w};
#pragma unroll
        for (int r = 0; r < 4; r++) {
            float d = xq + xcv[r] - 2.f * acc[r];
            if (d < d20[KNN - 1])
                insert20(d, n0 + quad * 4 + r, d20, i20);
        }
    }

#pragma unroll
    for (int j = 0; j < KNN; j++) {
        md[w][n][quad][j] = d20[j];
        mi[w][n][quad][j] = i20[j];
    }
    __syncthreads();
    if (L < 16) {
        int p[4] = {0, 0, 0, 0};
        long o = (((long)b * NSL + slice) * N_PTS + (q0 + qw + L)) * KNN;
#pragma unroll
        for (int j = 0; j < KNN; j++) {
            float best = FLT_MAX; int bi = 0x7fffffff; int bq = 0;
#pragma unroll
            for (int qd = 0; qd < 4; qd++) {
                float dv = md[w][L][qd][p[qd]];
                int   ci = mi[w][L][qd][p[qd]];
                if (dv < best || (dv == best && ci < bi)) { best = dv; bi = ci; bq = qd; }
            }
            knnd[o + j] = best;
            knni[o + j] = bi;
            p[bq]++;
        }
    }
}

// ---------------------------------------------------------------------------
// Merge the NSL sorted slice-lists per query into final idx[b][i][KNN]
// ---------------------------------------------------------------------------
__global__ void knn_merge8(const float* __restrict__ knnd, const int* __restrict__ knni,
                           int* __restrict__ idxOut)
{
    int id = blockIdx.x * 256 + threadIdx.x;   // b*N + i
    int b = id / N_PTS, i = id % N_PTS;
    const float* dl[NSL]; const int* il[NSL];
#pragma unroll
    for (int qt = 0; qt < NSL; qt++) {
        dl[qt] = knnd + (((long)b * NSL + qt) * N_PTS + i) * KNN;
        il[qt] = knni + (((long)b * NSL + qt) * N_PTS + i) * KNN;
    }
    int p[NSL];
#pragma unroll
    for (int qt = 0; qt < NSL; qt++) p[qt] = 0;
    int* o = idxOut + (long)id * KNN;
#pragma unroll
    for (int j = 0; j < KNN; j++) {
        float best = FLT_MAX; int bq = 0;
#pragma unroll
        for (int qt = 0; qt < NSL; qt++) {
            float vv = (p[qt] < KNN) ? dl[qt][p[qt]] : FLT_MAX;
            if (vv < best) { best = vv; bq = qt; }
        }
        o[j] = il[bq][p[bq]];
        p[bq]++;
    }
}

// ---------------------------------------------------------------------------
// Fused q/p MFMA GEMM (edge stages). A = point features (Ghi/Glo, [pt][k]),
// B = folded weights Wq/Wp bf16 hi/lo [cout][C]. Outputs point-major
// qv/pv [b][point][cout]; pv includes +shift.
// grid (N/64, cout/64, B), block 256 (4 waves x 16 points; 4 cout-chunks).
// ---------------------------------------------------------------------------
template<int KDP>
__global__ __launch_bounds__(256)
void qp_mfma(const unsigned short* __restrict__ Ghi,
             const unsigned short* __restrict__ Glo,
             const unsigned short* __restrict__ Wqh, const unsigned short* __restrict__ Wql,
             const unsigned short* __restrict__ Wph, const unsigned short* __restrict__ Wpl,
             const float* __restrict__ shf,
             float* __restrict__ qv, float* __restrict__ pv, int cout)
{
    constexpr int KS = KDP / 32;
    int tid = threadIdx.x;
    int w = tid >> 6, L = tid & 63;
    int n = L & 15, quad = L >> 4;
    int b = blockIdx.z;
    int p0 = blockIdx.x * 64 + w * 16;

    s8v ah[KS], al[KS];
    long abase = ((long)b * N_PTS + p0 + n) * KDP + quad * 8;
#pragma unroll
    for (int ks = 0; ks < KS; ks++) {
        ah[ks] = *(const s8v*)&Ghi[abase + ks * 32];
        al[ks] = *(const s8v*)&Glo[abase + ks * 32];
    }

#pragma unroll
    for (int oc4 = 0; oc4 < 4; oc4++) {
        int oc = blockIdx.y * 4 + oc4;
        long wbase = (long)(oc * 16 + n) * KDP + quad * 8;
        f4v aq = {0.f, 0.f, 0.f, 0.f};
        f4v ap = {0.f, 0.f, 0.f, 0.f};
#pragma unroll
        for (int ks = 0; ks < KS; ks++) {
            s8v wh = *(const s8v*)&Wqh[wbase + ks * 32];
            s8v wl = *(const s8v*)&Wql[wbase + ks * 32];
            aq = __builtin_amdgcn_mfma_f32_16x16x32_bf16(ah[ks], wh, aq, 0, 0, 0);
            aq = __builtin_amdgcn_mfma_f32_16x16x32_bf16(ah[ks], wl, aq, 0, 0, 0);
            aq = __builtin_amdgcn_mfma_f32_16x16x32_bf16(al[ks], wh, aq, 0, 0, 0);
            s8v ph = *(const s8v*)&Wph[wbase + ks * 32];
            s8v pl = *(const s8v*)&Wpl[wbase + ks * 32];
            ap = __builtin_amdgcn_mfma_f32_16x16x32_bf16(ah[ks], ph, ap, 0, 0, 0);
            ap = __builtin_amdgcn_mfma_f32_16x16x32_bf16(ah[ks], pl, ap, 0, 0, 0);
            ap = __builtin_amdgcn_mfma_f32_16x16x32_bf16(al[ks], ph, ap, 0, 0, 0);
        }
        float sv = shf[oc * 16 + n];
#pragma unroll
        for (int r = 0; r < 4; r++) {
            long pt = p0 + quad * 4 + r;
            long o = ((long)b * N_PTS + pt) * cout + oc * 16 + n;
            qv[o] = aq[r];
            pv[o] = ap[r] + sv;
        }
    }
}

// ---------------------------------------------------------------------------
// Stage-4 MFMA conv: Y[b][o][pt] = lrelu(sum_c W4[o][c]*cat[c][pt] + shift[o])
// A = W4 bf16 hi/lo [o][512]; B = catT bf16 hi/lo [b][pt][512].
// grid (N/16, B), block 256: 16 points shared, wave w owns o-chunks w*8..+7.
// ---------------------------------------------------------------------------
__global__ __launch_bounds__(256)
void conv4_mfma(const unsigned short* __restrict__ CTh, const unsigned short* __restrict__ CTl,
                const unsigned short* __restrict__ W4h, const unsigned short* __restrict__ W4l,
                const float* __restrict__ shf, float* __restrict__ Y)
{
    int tid = threadIdx.x;
    int w = tid >> 6, L = tid & 63;
    int n = L & 15, quad = L >> 4;
    int b = blockIdx.y;
    int p0 = blockIdx.x * 16;
    const unsigned short* cth = CTh + ((long)b * N_PTS + p0 + n) * 512 + quad * 8;
    const unsigned short* ctl = CTl + ((long)b * N_PTS + p0 + n) * 512 + quad * 8;

    f4v acc[8];
#pragma unroll
    for (int ch = 0; ch < 8; ch++) acc[ch] = {0.f, 0.f, 0.f, 0.f};

    for (int ks = 0; ks < 16; ks++) {
        s8v bh = *(const s8v*)&cth[ks * 32];
        s8v bl = *(const s8v*)&ctl[ks * 32];
#pragma unroll
        for (int ch = 0; ch < 8; ch++) {
            long o = (long)((w * 8 + ch) * 16 + n) * 512 + quad * 8 + ks * 32;
            s8v ahv = *(const s8v*)&W4h[o];
            s8v alv = *(const s8v*)&W4l[o];
            acc[ch] = __builtin_amdgcn_mfma_f32_16x16x32_bf16(ahv, bh, acc[ch], 0, 0, 0);
            acc[ch] = __builtin_amdgcn_mfma_f32_16x16x32_bf16(ahv, bl, acc[ch], 0, 0, 0);
            acc[ch] = __builtin_amdgcn_mfma_f32_16x16x32_bf16(alv, bh, acc[ch], 0, 0, 0);
        }
    }
#pragma unroll
    for (int ch = 0; ch < 8; ch++) {
#pragma unroll
        for (int r = 0; r < 4; r++) {
            int o = (w * 8 + ch) * 16 + quad * 4 + r;
            float y = acc[ch][r] + shf[o];
            y = y >= 0.f ? y : 0.2f * y;
            Y[((long)b * 512 + o) * N_PTS + p0 + n] = y;
        }
    }
}

// ---------------------------------------------------------------------------
// Weight folding to bf16 hi/lo, [o][c] layout (MFMA B-fragment order).
// ---------------------------------------------------------------------------
__global__ void fold_edge_bf16(const float* __restrict__ W, const float* __restrict__ g,
                               const float* __restrict__ bb, const float* __restrict__ m,
                               const float* __restrict__ v,
                               unsigned short* __restrict__ Wqh, unsigned short* __restrict__ Wql,
                               unsigned short* __restrict__ Wph, unsigned short* __restrict__ Wpl,
                               float* __restrict__ shift, int C, int cout)
{
    int id = blockIdx.x * 256 + threadIdx.x;
    if (id < C * cout) {
        int o = id / C;
        int c = id % C;
        float sc = g[o] * rsqrtf(v[o] + EPSB);
        float wd = W[(long)o * 2 * C + c];
        float wc = W[(long)o * 2 * C + C + c];
        bf16split(sc * wd, &Wqh[id], &Wql[id]);
        bf16split(sc * (wc - wd), &Wph[id], &Wpl[id]);
    }
    if (id < cout) {
        float sc = g[id] * rsqrtf(v[id] + EPSB);
        shift[id] = bb[id] - m[id] * sc;
    }
}

__global__ void fold_plain_bf16(const float* __restrict__ W, const float* __restrict__ g,
                                const float* __restrict__ bb, const float* __restrict__ m,
                                const float* __restrict__ v,
                                unsigned short* __restrict__ W4h, unsigned short* __restrict__ W4l,
                                float* __restrict__ shift, int C, int cout)
{
    int id = blockIdx.x * 256 + threadIdx.x;
    if (id < C * cout) {
        int o = id / C;
        int c = id % C;
        float sc = g[o] * rsqrtf(v[o] + EPSB);
        bf16split(sc * W[(long)o * C + c], &W4h[id], &W4l[id]);
    }
    if (id < cout) {
        float sc = g[id] * rsqrtf(v[id] + EPSB);
        shift[id] = bb[id] - m[id] * sc;
    }
}

// ---------------------------------------------------------------------------
__global__ void prep_xt_kernel(const float* __restrict__ x, float* __restrict__ xt)
{
    int id = blockIdx.x * 256 + threadIdx.x;    // < 4*3*4096
    int b = id / (3 * N_PTS);
    int rem = id % (3 * N_PTS);
    int c = rem / N_PTS;
    int i = rem % N_PTS;
    xt[id] = x[((long)b * N_PTS + i) * 3 + c];
}

__global__ void sqnorm_kernel(const float* __restrict__ F, float* __restrict__ xx,
                              int C, long bsF)
{
    int b = blockIdx.y;
    int j = blockIdx.x * 256 + threadIdx.x;
    const float* f = F + (long)b * bsF;
    float s = 0.f;
    for (int c = 0; c < C; c++) {
        float t = f[(long)c * N_PTS + j];
        s = fmaf(t, t, s);
    }
    xx[(long)b * N_PTS + j] = s;
}

__global__ void gather_max_kernel(const float* __restrict__ q, const float* __restrict__ p,
                                  const int* __restrict__ idx, float* __restrict__ cat,
                                  int cout, int c_off)
{
    int b = blockIdx.y;
    int i = blockIdx.x * 4 + threadIdx.y;
    int tx = threadIdx.x;
    const int* ip = idx + ((long)b * N_PTS + i) * KNN;
    int js[KNN];
#pragma unroll
    for (int k = 0; k < KNN; k++) js[k] = ip[k];
    const float* qb = q + (long)b * N_PTS * cout;
    const float* pb = p + ((long)b * N_PTS + i) * cout;
    float* ob = cat + ((long)b * 512 + c_off) * N_PTS + i;
    for (int o0 = 0; o0 < cout; o0 += 64) {
        int o = o0 + tx;
        float pv = pb[o];
        float mx = -FLT_MAX;
#pragma unroll
        for (int k = 0; k < KNN; k++) {
            float val = qb[(long)js[k] * cout + o] + pv;
            val = val >= 0.f ? val : 0.2f * val;
            mx = fmaxf(mx, val);
        }
        ob[(long)o * N_PTS] = mx;
    }
}

__global__ void edge0_kernel(const float* __restrict__ xt, const int* __restrict__ idx,
                             const float* __restrict__ W0, const float* __restrict__ g0,
                             const float* __restrict__ b0, const float* __restrict__ m0,
                             const float* __restrict__ v0, float* __restrict__ cat)
{
    int b = blockIdx.y;
    int i = blockIdx.x * 4 + threadIdx.y;
    int o = threadIdx.x;
    const float* xb = xt + (long)b * 3 * N_PTS;
    float cx = xb[i], cy = xb[N_PTS + i], cz = xb[2 * N_PTS + i];
    float w[9];
#pragma unroll
    for (int c = 0; c < 9; c++) w[c] = W0[o * 9 + c];
    float sc = g0[o] * rsqrtf(v0[o] + EPSB);
    float sh = b0[o] - m0[o] * sc;
    const int* ip = idx + ((long)b * N_PTS + i) * KNN;
    float mx = -FLT_MAX;
#pragma unroll
    for (int k = 0; k < KNN; k++) {
        int j = ip[k];
        float nx = xb[j], ny = xb[N_PTS + j], nz = xb[2 * N_PTS + j];
        float dx = nx - cx, dy = ny - cy, dz = nz - cz;
        float crx = cy * nz - cz * ny;
        float cry = cz * nx - cx * nz;
        float crz = cx * ny - cy * nx;
        float y = w[0] * dx + w[1] * dy + w[2] * dz
                + w[3] * crx + w[4] * cry + w[5] * crz
                + w[6] * cx + w[7] * cy + w[8] * cz;
        y = y * sc + sh;
        y = y >= 0.f ? y : 0.2f * y;
        mx = fmaxf(mx, y);
    }
    cat[((long)b * 512 + o) * N_PTS + i] = mx;
}

__global__ void rowmax_kernel(const float* __restrict__ Y, float* __restrict__ ymax)
{
    __shared__ float red[256];
    int b = blockIdx.y, o = blockIdx.x, t = threadIdx.x;
    const float* yb = Y + ((long)b * 512 + o) * N_PTS;
    float mx = -FLT_MAX;
#pragma unroll
    for (int s = 0; s < N_PTS / 256; s++) mx = fmaxf(mx, yb[t + 256 * s]);
    red[t] = mx;
    __syncthreads();
    for (int off = 128; off > 0; off >>= 1) {
        if (t < off) red[t] = fmaxf(red[t], red[t + off]);
        __syncthreads();
    }
    if (t == 0) ymax[(long)b * 512 + o] = red[0];
}

__global__ void head_kernel(const float* __restrict__ ymax, const float* __restrict__ We,
                            const float* __restrict__ Wh, const float* __restrict__ bh,
                            float* __restrict__ out)
{
    __shared__ float emb[128];
    __shared__ float yv[512];
    int b = blockIdx.x, t = threadIdx.x;
    for (int s = t; s < 512; s += 128) yv[s] = ymax[(long)b * 512 + s];
    __syncthreads();
    float acc = 0.f;
    for (int c = 0; c < 512; c++) acc = fmaf(yv[c], We[(long)t * 512 + c], acc);
    emb[t] = acc;
    __syncthreads();
    float acc2 = bh[t];
    for (int ff = 0; ff < 128; ff++) acc2 = fmaf(emb[ff], Wh[(long)t * 128 + ff], acc2);
    out[(long)b * 128 + t] = acc2;
}

// ---------------------------------------------------------------------------
extern "C" void kernel_launch(void* const* d_in, const int* in_sizes, int n_in,
                              void* d_out, int out_size, void* d_ws, size_t ws_size,
                              hipStream_t stream)
{
    const float* x = (const float*)d_in[0];
    const float *W[5], *g[5], *bb[5], *m[5], *v[5];
    for (int li = 0; li < 5; li++) {
        W[li]  = (const float*)d_in[1 + li * 5 + 0];
        g[li]  = (const float*)d_in[1 + li * 5 + 1];
        bb[li] = (const float*)d_in[1 + li * 5 + 2];
        m[li]  = (const float*)d_in[1 + li * 5 + 3];
        v[li]  = (const float*)d_in[1 + li * 5 + 4];
    }
    const float* We = (const float*)d_in[26];
    const float* Wh = (const float*)d_in[27];
    const float* bh = (const float*)d_in[28];
    float* out = (float*)d_out;

    // workspace carve (float units). Peak ~86 MB (< 104 MB proven in R0).
    float* ws   = (float*)d_ws;
    float* cat  = ws;                                   // 8,388,608 (B,512,N); stage4 Y reuses
    float* qbuf = cat + (long)8388608;                  // 8,388,608 multi-purpose
    float* pbuf = qbuf + (long)8388608;                 // 4,194,304 (p-values)
    int*   idxb = (int*)(pbuf + 4194304);               // 327,680 ints
    float* xt   = (float*)(idxb + 327680);              // 49,152
    float* xx   = xt + 49152;                           // 16,384
    unsigned short* Wqh = (unsigned short*)(xx + 16384);// 32,768 shorts each
    unsigned short* Wql = Wqh + 32768;
    unsigned short* Wph = Wql + 32768;
    unsigned short* Wpl = Wph + 32768;
    unsigned short* W4h = Wpl + 32768;                  // 262,144 shorts
    unsigned short* W4l = W4h + 262144;
    float* shf  = (float*)(W4l + 262144);               // 512
    float* ymax = shf + 512;                            // 2,048
    // qbuf internal layout:
    //  [0 .. 2,097,152) floats: Ghi/Glo (per-stage bf16 hi/lo, KDP<=128)
    //  [2,097,152 .. 7,340,032): knn slice lists (dead before qv written)
    //  [2,097,152 .. 6,291,456): qv (q-values, point-major)  [after knn]
    //  stage4: whole qbuf = catT hi (16MB) + catT lo (16MB)
    unsigned short* Ghi = (unsigned short*)qbuf;        // 2,097,152 shorts max
    unsigned short* Glo = Ghi + 2097152;
    float* knnd = qbuf + 2097152;                       // 2,621,440 floats
    int*   knni = (int*)(qbuf + 2097152 + 2621440);     // 2,621,440 ints
    float* qv   = qbuf + 2097152;                       // 4,194,304 floats
    unsigned short* CTh = (unsigned short*)qbuf;        // 8,388,608 shorts
    unsigned short* CTl = CTh + 8388608;

    // ---- prep ----
    prep_xt_kernel<<<dim3(192), dim3(256), 0, stream>>>(x, xt);

    // ---- stage 0: knn on coords (C=3, K padded to 32) ----
    sqnorm_kernel<<<dim3(16, NB), dim3(256), 0, stream>>>(xt, xx, 3, (long)3 * N_PTS);
    to_bf16_tr<<<dim3(64, NB), dim3(256), 0, stream>>>(
        xt, (long)3 * N_PTS, 3, 32, Ghi, Glo);
    fused_knn_mfma2<32><<<dim3(64, NSL, NB), dim3(256), 0, stream>>>(
        Ghi, Glo, xx, knnd, knni);
    knn_merge8<<<dim3(64), dim3(256), 0, stream>>>(knnd, knni, idxb);
    edge0_kernel<<<dim3(N_PTS / 4, NB), dim3(64, 4), 0, stream>>>(
        xt, idxb, W[0], g[0], bb[0], m[0], v[0], cat);

    // ---- stages 1..3 ----
    const int Cs_[3]   = {64, 64, 128};
    const int co_[3]   = {64, 128, 256};
    const int inO_[3]  = {0, 64, 128};
    const int outO_[3] = {64, 128, 256};
    for (int s = 0; s < 3; s++) {
        int C = Cs_[s], cout = co_[s];
        const float* F = cat + (long)inO_[s] * N_PTS;   // batch stride 512*N
        sqnorm_kernel<<<dim3(16, NB), dim3(256), 0, stream>>>(F, xx, C, (long)512 * N_PTS);
        to_bf16_tr<<<dim3(64, NB), dim3(256), 0, stream>>>(
            F, (long)512 * N_PTS, C, C, Ghi, Glo);
        if (C == 64)
            fused_knn_mfma2<64><<<dim3(64, NSL, NB), dim3(256), 0, stream>>>(
                Ghi, Glo, xx, knnd, knni);
        else
            fused_knn_mfma2<128><<<dim3(64, NSL, NB), dim3(256), 0, stream>>>(
                Ghi, Glo, xx, knnd, knni);
        knn_merge8<<<dim3(64), dim3(256), 0, stream>>>(knnd, knni, idxb);

        int li = s + 1;
        fold_edge_bf16<<<dim3((C * cout + 255) / 256), dim3(256), 0, stream>>>(
            W[li], g[li], bb[li], m[li], v[li], Wqh, Wql, Wph, Wpl, shf, C, cout);
        if (C == 64)
            qp_mfma<64><<<dim3(64, cout / 64, NB), dim3(256), 0, stream>>>(
                Ghi, Glo, Wqh, Wql, Wph, Wpl, shf, qv, pbuf, cout);
        else
            qp_mfma<128><<<dim3(64, cout / 64, NB), dim3(256), 0, stream>>>(
                Ghi, Glo, Wqh, Wql, Wph, Wpl, shf, qv, pbuf, cout);
        gather_max_kernel<<<dim3(N_PTS / 4, NB), dim3(64, 4), 0, stream>>>(
            qv, pbuf, idxb, cat, cout, outO_[s]);
    }

    // ---- stage 4: MFMA pointwise conv + bn + lrelu ----
    fold_plain_bf16<<<dim3((512 * 512 + 255) / 256), dim3(256), 0, stream>>>(
        W[4], g[4], bb[4], m[4], v[4], W4h, W4l, shf, 512, 512);
    to_bf16_tr<<<dim3(64, NB), dim3(256), 0, stream>>>(
        cat, (long)512 * N_PTS, 512, 512, CTh, CTl);
    conv4_mfma<<<dim3(N_PTS / 16, NB), dim3(256), 0, stream>>>(
        CTh, CTl, W4h, W4l, shf, cat);   // Y overwrites dead fp32 cat

    // ---- global max + head ----
    rowmax_kernel<<<dim3(512, NB), dim3(256), 0, stream>>>(cat, ymax);
    head_kernel<<<dim3(NB), dim3(128), 0, stream>>>(ymax, We, Wh, bh, out);
}

// Round 11
// 1355.190 us; speedup vs baseline: 1.8216x; 1.2197x over previous
//
#include <hip/hip_runtime.h>
#include <cfloat>

#define N_PTS 4096
#define NB    4
#define KNN   20
#define EPSB  1e-5f
#define NSL   4          // knn candidate slices per batch-row

typedef short s8v __attribute__((ext_vector_type(8)));
typedef float f4v __attribute__((ext_vector_type(4)));

// ---------------------------------------------------------------------------
// bf16 hi/lo split (round-to-nearest-even both halves)
// ---------------------------------------------------------------------------
__device__ __forceinline__ void bf16split(float x, unsigned short* h, unsigned short* l)
{
    unsigned u = __builtin_bit_cast(unsigned, x);
    unsigned hb = (u + 0x7fffu + ((u >> 16) & 1u)) >> 16;
    float hf = __builtin_bit_cast(float, hb << 16);
    float res = x - hf;
    unsigned u2 = __builtin_bit_cast(unsigned, res);
    unsigned lb = (u2 + 0x7fffu + ((u2 >> 16) & 1u)) >> 16;
    *h = (unsigned short)hb;
    *l = (unsigned short)lb;
}

// ---------------------------------------------------------------------------
// Packed key: fp32 distance (top 24 bits: sign+exp+15 mantissa) | 8-bit
// lane-local candidate ordinal. d>=0 after clamp -> bit order == value order.
// 15 mantissa bits => 2^-15 ranking perturbation (R10's 11-bit variant FAILED
// at 0.44 absmax; 2^-16 hi/lo error passed at 0.03 - this sits at the same
// scale as the accepted error).
// ---------------------------------------------------------------------------
__device__ __forceinline__ unsigned packkey(float d, int lc)
{
    d = fmaxf(d, 0.f);
    unsigned u = __builtin_bit_cast(unsigned, d);
    return (u & 0xFFFFFF00u) | (unsigned)lc;
}

// Branch-free sorted-insert: ascending bubble, 20x (v_min_u32 + v_max_u32).
// Run unconditionally every step (wave-level insert probability is ~1).
__device__ __forceinline__ void insert20k(unsigned key, unsigned (&k20)[KNN])
{
#pragma unroll
    for (int j = 0; j < KNN; j++) {
        unsigned old = k20[j];
        unsigned lo = old < key ? old : key;
        key = old < key ? key : old;
        k20[j] = lo;
    }
}

// ---------------------------------------------------------------------------
// fp32 -> bf16 hi/lo split, transposed to [b][point][k] (MFMA fragment order).
// grid (N/64, B), block 256 (64 points x 4 k-octets). k >= C zero-filled.
// ---------------------------------------------------------------------------
__global__ __launch_bounds__(256)
void to_bf16_tr(const float* __restrict__ F, long bsF, int C, int KDP,
                unsigned short* __restrict__ Ghi, unsigned short* __restrict__ Glo)
{
    int b = blockIdx.y;
    int n = blockIdx.x * 64 + (threadIdx.x & 63);
    int kq = threadIdx.x >> 6;
    const float* Fb = F + (long)b * bsF;
    for (int k0 = kq * 8; k0 < KDP; k0 += 32) {
        s8v hv, lv;
#pragma unroll
        for (int i = 0; i < 8; i++) {
            int k = k0 + i;
            float x = (k < C) ? Fb[(long)k * N_PTS + n] : 0.f;
            unsigned short h, l;
            bf16split(x, &h, &l);
            hv[i] = (short)h;
            lv[i] = (short)l;
        }
        long o = ((long)b * N_PTS + n) * KDP + k0;
        *(s8v*)&Ghi[o] = hv;
        *(s8v*)&Glo[o] = lv;
    }
}

// ---------------------------------------------------------------------------
// MFMA fused distance + top-20, packed-key in-register selection.
// grid (N/64, NSL, B), block 256 (4 waves, one barrier pair total).
// Wave w: 16 queries x 1024 slice-candidates. Lane L: fixed query n=L&15,
// candidates quad*4+r per acc register (quad=L>>4) -> per-lane slice = 256
// candidates, lane-local ordinal lc = t*4+r (8 bits).
// Selection: packed u32 keys, unconditional 40-inst min/max bubble.
// Epilogue: per-wave LDS merge of 4 quad lists; global index reconstructed
// from (slice, quad, lc); ties broken by lower global index.
// Out: knnd/knni [b][slice][N][KNN] sorted ascending (truncated dist).
// ---------------------------------------------------------------------------
template<int KDP>
__global__ __launch_bounds__(256)
void fused_knn_mfma3(const unsigned short* __restrict__ Ghi,
                     const unsigned short* __restrict__ Glo,
                     const float* __restrict__ xx,
                     float* __restrict__ knnd, int* __restrict__ knni)
{
    constexpr int KS = KDP / 32;
    __shared__ unsigned mk[4][16][4][KNN];   // 20,480 B

    int tid = threadIdx.x;
    int w = tid >> 6, L = tid & 63;
    int n = L & 15;
    int quad = L >> 4;
    int b = blockIdx.z, slice = blockIdx.y;
    int q0 = blockIdx.x * 64, qw = w * 16;
    const unsigned short* Gh = Ghi + (long)b * N_PTS * KDP;
    const unsigned short* Gl = Glo + (long)b * N_PTS * KDP;
    const float* xxb = xx + (long)b * N_PTS;

    // persistent query fragments (hi+lo, all k-steps)
    s8v qhi[KS], qlo[KS];
    long qbase = (long)(q0 + qw + n) * KDP + quad * 8;
#pragma unroll
    for (int ks = 0; ks < KS; ks++) {
        qhi[ks] = *(const s8v*)&Gh[qbase + ks * 32];
        qlo[ks] = *(const s8v*)&Gl[qbase + ks * 32];
    }
    float xq = xxb[q0 + qw + n];

    unsigned k20[KNN];
#pragma unroll
    for (int j = 0; j < KNN; j++) k20[j] = 0xFFFFFFFFu;

    // running offsets (incremented per tile)
    long coff = (long)(slice * 1024 + n) * KDP + quad * 8;
    const float* xcp = xxb + slice * 1024 + quad * 4;

    for (int t = 0; t < 64; t++) {
        f4v acc = {0.f, 0.f, 0.f, 0.f};
#pragma unroll
        for (int ks = 0; ks < KS; ks++) {
            s8v chi = *(const s8v*)&Gh[coff + ks * 32];
            s8v clo = *(const s8v*)&Gl[coff + ks * 32];
            acc = __builtin_amdgcn_mfma_f32_16x16x32_bf16(chi, qhi[ks], acc, 0, 0, 0);
            acc = __builtin_amdgcn_mfma_f32_16x16x32_bf16(chi, qlo[ks], acc, 0, 0, 0);
            acc = __builtin_amdgcn_mfma_f32_16x16x32_bf16(clo, qhi[ks], acc, 0, 0, 0);
        }
        float4 xc4 = *(const float4*)xcp;
        float xcv[4] = {xc4.x, xc4.y, xc4.z, xc4.w};
#pragma unroll
        for (int r = 0; r < 4; r++) {
            float d = xq + xcv[r] - 2.f * acc[r];
            insert20k(packkey(d, t * 4 + r), k20);
        }
        coff += 16 * KDP;
        xcp += 16;
    }

    // publish per-lane lists, then 16 owner lanes merge 4 quad-slices/query
#pragma unroll
    for (int j = 0; j < KNN; j++) mk[w][n][quad][j] = k20[j];
    __syncthreads();
    if (L < 16) {
        int p[4] = {0, 0, 0, 0};
        long o = (((long)b * NSL + slice) * N_PTS + (q0 + qw + L)) * KNN;
#pragma unroll
        for (int j = 0; j < KNN; j++) {
            unsigned bd = 0xFFFFFF00u; int bi = 0x7fffffff; int bq = 0;
#pragma unroll
            for (int qd = 0; qd < 4; qd++) {
                unsigned kk = mk[w][L][qd][p[qd]];
                unsigned db = kk & 0xFFFFFF00u;
                int lc = (int)(kk & 0xFFu);
                int ci = slice * 1024 + (lc >> 2) * 16 + qd * 4 + (lc & 3);
                if (db < bd || (db == bd && ci < bi)) { bd = db; bi = ci; bq = qd; }
            }
            knnd[o + j] = __builtin_bit_cast(float, bd);
            knni[o + j] = bi;
            p[bq]++;
        }
    }
}

// ---------------------------------------------------------------------------
// Merge the NSL sorted slice lists per query -> final idx[b][i][KNN].
// Ties (equal truncated distance) broken by lower global index.
// ---------------------------------------------------------------------------
__global__ void knn_merge4(const float* __restrict__ knnd, const int* __restrict__ knni,
                           int* __restrict__ idxOut)
{
    int id = blockIdx.x * 256 + threadIdx.x;   // b*N + i
    int b = id / N_PTS, i = id % N_PTS;
    const float* dl[NSL]; const int* il[NSL];
#pragma unroll
    for (int qt = 0; qt < NSL; qt++) {
        dl[qt] = knnd + (((long)b * NSL + qt) * N_PTS + i) * KNN;
        il[qt] = knni + (((long)b * NSL + qt) * N_PTS + i) * KNN;
    }
    int p[NSL];
#pragma unroll
    for (int qt = 0; qt < NSL; qt++) p[qt] = 0;
    int* o = idxOut + (long)id * KNN;
#pragma unroll
    for (int j = 0; j < KNN; j++) {
        float best = FLT_MAX; int bi = 0x7fffffff; int bq = 0;
#pragma unroll
        for (int qt = 0; qt < NSL; qt++) {
            float vv = (p[qt] < KNN) ? dl[qt][p[qt]] : FLT_MAX;
            int   ci = (p[qt] < KNN) ? il[qt][p[qt]] : 0x7fffffff;
            if (vv < best || (vv == best && ci < bi)) { best = vv; bi = ci; bq = qt; }
        }
        o[j] = bi;
        p[bq]++;
    }
}

// ---------------------------------------------------------------------------
// Fused q/p MFMA GEMM (edge stages). A = point features (Ghi/Glo, [pt][k]),
// B = folded weights Wq/Wp bf16 hi/lo [cout][C]. Outputs point-major
// qv/pv [b][point][cout]; pv includes +shift.
// grid (N/64, cout/64, B), block 256 (4 waves x 16 points; 4 cout-chunks).
// ---------------------------------------------------------------------------
template<int KDP>
__global__ __launch_bounds__(256)
void qp_mfma(const unsigned short* __restrict__ Ghi,
             const unsigned short* __restrict__ Glo,
             const unsigned short* __restrict__ Wqh, const unsigned short* __restrict__ Wql,
             const unsigned short* __restrict__ Wph, const unsigned short* __restrict__ Wpl,
             const float* __restrict__ shf,
             float* __restrict__ qv, float* __restrict__ pv, int cout)
{
    constexpr int KS = KDP / 32;
    int tid = threadIdx.x;
    int w = tid >> 6, L = tid & 63;
    int n = L & 15, quad = L >> 4;
    int b = blockIdx.z;
    int p0 = blockIdx.x * 64 + w * 16;

    s8v ah[KS], al[KS];
    long abase = ((long)b * N_PTS + p0 + n) * KDP + quad * 8;
#pragma unroll
    for (int ks = 0; ks < KS; ks++) {
        ah[ks] = *(const s8v*)&Ghi[abase + ks * 32];
        al[ks] = *(const s8v*)&Glo[abase + ks * 32];
    }

#pragma unroll
    for (int oc4 = 0; oc4 < 4; oc4++) {
        int oc = blockIdx.y * 4 + oc4;
        long wbase = (long)(oc * 16 + n) * KDP + quad * 8;
        f4v aq = {0.f, 0.f, 0.f, 0.f};
        f4v ap = {0.f, 0.f, 0.f, 0.f};
#pragma unroll
        for (int ks = 0; ks < KS; ks++) {
            s8v wh = *(const s8v*)&Wqh[wbase + ks * 32];
            s8v wl = *(const s8v*)&Wql[wbase + ks * 32];
            aq = __builtin_amdgcn_mfma_f32_16x16x32_bf16(ah[ks], wh, aq, 0, 0, 0);
            aq = __builtin_amdgcn_mfma_f32_16x16x32_bf16(ah[ks], wl, aq, 0, 0, 0);
            aq = __builtin_amdgcn_mfma_f32_16x16x32_bf16(al[ks], wh, aq, 0, 0, 0);
            s8v ph = *(const s8v*)&Wph[wbase + ks * 32];
            s8v pl = *(const s8v*)&Wpl[wbase + ks * 32];
            ap = __builtin_amdgcn_mfma_f32_16x16x32_bf16(ah[ks], ph, ap, 0, 0, 0);
            ap = __builtin_amdgcn_mfma_f32_16x16x32_bf16(ah[ks], pl, ap, 0, 0, 0);
            ap = __builtin_amdgcn_mfma_f32_16x16x32_bf16(al[ks], ph, ap, 0, 0, 0);
        }
        float sv = shf[oc * 16 + n];
#pragma unroll
        for (int r = 0; r < 4; r++) {
            long pt = p0 + quad * 4 + r;
            long o = ((long)b * N_PTS + pt) * cout + oc * 16 + n;
            qv[o] = aq[r];
            pv[o] = ap[r] + sv;
        }
    }
}

// ---------------------------------------------------------------------------
// Stage-4 MFMA conv: Y[b][o][pt] = lrelu(sum_c W4[o][c]*cat[c][pt] + shift[o])
// A = W4 bf16 hi/lo [o][512]; B = catT bf16 hi/lo [b][pt][512].
// grid (N/16, B), block 256: 16 points shared, wave w owns o-chunks w*8..+7.
// ---------------------------------------------------------------------------
__global__ __launch_bounds__(256)
void conv4_mfma(const unsigned short* __restrict__ CTh, const unsigned short* __restrict__ CTl,
                const unsigned short* __restrict__ W4h, const unsigned short* __restrict__ W4l,
                const float* __restrict__ shf, float* __restrict__ Y)
{
    int tid = threadIdx.x;
    int w = tid >> 6, L = tid & 63;
    int n = L & 15, quad = L >> 4;
    int b = blockIdx.y;
    int p0 = blockIdx.x * 16;
    const unsigned short* cth = CTh + ((long)b * N_PTS + p0 + n) * 512 + quad * 8;
    const unsigned short* ctl = CTl + ((long)b * N_PTS + p0 + n) * 512 + quad * 8;

    f4v acc[8];
#pragma unroll
    for (int ch = 0; ch < 8; ch++) acc[ch] = {0.f, 0.f, 0.f, 0.f};

    for (int ks = 0; ks < 16; ks++) {
        s8v bh = *(const s8v*)&cth[ks * 32];
        s8v bl = *(const s8v*)&ctl[ks * 32];
#pragma unroll
        for (int ch = 0; ch < 8; ch++) {
            long o = (long)((w * 8 + ch) * 16 + n) * 512 + quad * 8 + ks * 32;
            s8v ahv = *(const s8v*)&W4h[o];
            s8v alv = *(const s8v*)&W4l[o];
            acc[ch] = __builtin_amdgcn_mfma_f32_16x16x32_bf16(ahv, bh, acc[ch], 0, 0, 0);
            acc[ch] = __builtin_amdgcn_mfma_f32_16x16x32_bf16(ahv, bl, acc[ch], 0, 0, 0);
            acc[ch] = __builtin_amdgcn_mfma_f32_16x16x32_bf16(alv, bh, acc[ch], 0, 0, 0);
        }
    }
#pragma unroll
    for (int ch = 0; ch < 8; ch++) {
#pragma unroll
        for (int r = 0; r < 4; r++) {
            int o = (w * 8 + ch) * 16 + quad * 4 + r;
            float y = acc[ch][r] + shf[o];
            y = y >= 0.f ? y : 0.2f * y;
            Y[((long)b * 512 + o) * N_PTS + p0 + n] = y;
        }
    }
}

// ---------------------------------------------------------------------------
// Weight folding to bf16 hi/lo, [o][c] layout (MFMA B-fragment order).
// ---------------------------------------------------------------------------
__global__ void fold_edge_bf16(const float* __restrict__ W, const float* __restrict__ g,
                               const float* __restrict__ bb, const float* __restrict__ m,
                               const float* __restrict__ v,
                               unsigned short* __restrict__ Wqh, unsigned short* __restrict__ Wql,
                               unsigned short* __restrict__ Wph, unsigned short* __restrict__ Wpl,
                               float* __restrict__ shift, int C, int cout)
{
    int id = blockIdx.x * 256 + threadIdx.x;
    if (id < C * cout) {
        int o = id / C;
        int c = id % C;
        float sc = g[o] * rsqrtf(v[o] + EPSB);
        float wd = W[(long)o * 2 * C + c];
        float wc = W[(long)o * 2 * C + C + c];
        bf16split(sc * wd, &Wqh[id], &Wql[id]);
        bf16split(sc * (wc - wd), &Wph[id], &Wpl[id]);
    }
    if (id < cout) {
        float sc = g[id] * rsqrtf(v[id] + EPSB);
        shift[id] = bb[id] - m[id] * sc;
    }
}

__global__ void fold_plain_bf16(const float* __restrict__ W, const float* __restrict__ g,
                                const float* __restrict__ bb, const float* __restrict__ m,
                                const float* __restrict__ v,
                                unsigned short* __restrict__ W4h, unsigned short* __restrict__ W4l,
                                float* __restrict__ shift, int C, int cout)
{
    int id = blockIdx.x * 256 + threadIdx.x;
    if (id < C * cout) {
        int o = id / C;
        int c = id % C;
        float sc = g[o] * rsqrtf(v[o] + EPSB);
        bf16split(sc * W[(long)o * C + c], &W4h[id], &W4l[id]);
    }
    if (id < cout) {
        float sc = g[id] * rsqrtf(v[id] + EPSB);
        shift[id] = bb[id] - m[id] * sc;
    }
}

// ---------------------------------------------------------------------------
__global__ void prep_xt_kernel(const float* __restrict__ x, float* __restrict__ xt)
{
    int id = blockIdx.x * 256 + threadIdx.x;    // < 4*3*4096
    int b = id / (3 * N_PTS);
    int rem = id % (3 * N_PTS);
    int c = rem / N_PTS;
    int i = rem % N_PTS;
    xt[id] = x[((long)b * N_PTS + i) * 3 + c];
}

__global__ void sqnorm_kernel(const float* __restrict__ F, float* __restrict__ xx,
                              int C, long bsF)
{
    int b = blockIdx.y;
    int j = blockIdx.x * 256 + threadIdx.x;
    const float* f = F + (long)b * bsF;
    float s = 0.f;
    for (int c = 0; c < C; c++) {
        float t = f[(long)c * N_PTS + j];
        s = fmaf(t, t, s);
    }
    xx[(long)b * N_PTS + j] = s;
}

__global__ void gather_max_kernel(const float* __restrict__ q, const float* __restrict__ p,
                                  const int* __restrict__ idx, float* __restrict__ cat,
                                  int cout, int c_off)
{
    int b = blockIdx.y;
    int i = blockIdx.x * 4 + threadIdx.y;
    int tx = threadIdx.x;
    const int* ip = idx + ((long)b * N_PTS + i) * KNN;
    int js[KNN];
#pragma unroll
    for (int k = 0; k < KNN; k++) js[k] = ip[k];
    const float* qb = q + (long)b * N_PTS * cout;
    const float* pb = p + ((long)b * N_PTS + i) * cout;
    float* ob = cat + ((long)b * 512 + c_off) * N_PTS + i;
    for (int o0 = 0; o0 < cout; o0 += 64) {
        int o = o0 + tx;
        float pv = pb[o];
        float mx = -FLT_MAX;
#pragma unroll
        for (int k = 0; k < KNN; k++) {
            float val = qb[(long)js[k] * cout + o] + pv;
            val = val >= 0.f ? val : 0.2f * val;
            mx = fmaxf(mx, val);
        }
        ob[(long)o * N_PTS] = mx;
    }
}

__global__ void edge0_kernel(const float* __restrict__ xt, const int* __restrict__ idx,
                             const float* __restrict__ W0, const float* __restrict__ g0,
                             const float* __restrict__ b0, const float* __restrict__ m0,
                             const float* __restrict__ v0, float* __restrict__ cat)
{
    int b = blockIdx.y;
    int i = blockIdx.x * 4 + threadIdx.y;
    int o = threadIdx.x;
    const float* xb = xt + (long)b * 3 * N_PTS;
    float cx = xb[i], cy = xb[N_PTS + i], cz = xb[2 * N_PTS + i];
    float w[9];
#pragma unroll
    for (int c = 0; c < 9; c++) w[c] = W0[o * 9 + c];
    float sc = g0[o] * rsqrtf(v0[o] + EPSB);
    float sh = b0[o] - m0[o] * sc;
    const int* ip = idx + ((long)b * N_PTS + i) * KNN;
    float mx = -FLT_MAX;
#pragma unroll
    for (int k = 0; k < KNN; k++) {
        int j = ip[k];
        float nx = xb[j], ny = xb[N_PTS + j], nz = xb[2 * N_PTS + j];
        float dx = nx - cx, dy = ny - cy, dz = nz - cz;
        float crx = cy * nz - cz * ny;
        float cry = cz * nx - cx * nz;
        float crz = cx * ny - cy * nx;
        float y = w[0] * dx + w[1] * dy + w[2] * dz
                + w[3] * crx + w[4] * cry + w[5] * crz
                + w[6] * cx + w[7] * cy + w[8] * cz;
        y = y * sc + sh;
        y = y >= 0.f ? y : 0.2f * y;
        mx = fmaxf(mx, y);
    }
    cat[((long)b * 512 + o) * N_PTS + i] = mx;
}

__global__ void rowmax_kernel(const float* __restrict__ Y, float* __restrict__ ymax)
{
    __shared__ float red[256];
    int b = blockIdx.y, o = blockIdx.x, t = threadIdx.x;
    const float* yb = Y + ((long)b * 512 + o) * N_PTS;
    float mx = -FLT_MAX;
#pragma unroll
    for (int s = 0; s < N_PTS / 256; s++) mx = fmaxf(mx, yb[t + 256 * s]);
    red[t] = mx;
    __syncthreads();
    for (int off = 128; off > 0; off >>= 1) {
        if (t < off) red[t] = fmaxf(red[t], red[t + off]);
        __syncthreads();
    }
    if (t == 0) ymax[(long)b * 512 + o] = red[0];
}

__global__ void head_kernel(const float* __restrict__ ymax, const float* __restrict__ We,
                            const float* __restrict__ Wh, const float* __restrict__ bh,
                            float* __restrict__ out)
{
    __shared__ float emb[128];
    __shared__ float yv[512];
    int b = blockIdx.x, t = threadIdx.x;
    for (int s = t; s < 512; s += 128) yv[s] = ymax[(long)b * 512 + s];
    __syncthreads();
    float acc = 0.f;
    for (int c = 0; c < 512; c++) acc = fmaf(yv[c], We[(long)t * 512 + c], acc);
    emb[t] = acc;
    __syncthreads();
    float acc2 = bh[t];
    for (int ff = 0; ff < 128; ff++) acc2 = fmaf(emb[ff], Wh[(long)t * 128 + ff], acc2);
    out[(long)b * 128 + t] = acc2;
}

// ---------------------------------------------------------------------------
extern "C" void kernel_launch(void* const* d_in, const int* in_sizes, int n_in,
                              void* d_out, int out_size, void* d_ws, size_t ws_size,
                              hipStream_t stream)
{
    const float* x = (const float*)d_in[0];
    const float *W[5], *g[5], *bb[5], *m[5], *v[5];
    for (int li = 0; li < 5; li++) {
        W[li]  = (const float*)d_in[1 + li * 5 + 0];
        g[li]  = (const float*)d_in[1 + li * 5 + 1];
        bb[li] = (const float*)d_in[1 + li * 5 + 2];
        m[li]  = (const float*)d_in[1 + li * 5 + 3];
        v[li]  = (const float*)d_in[1 + li * 5 + 4];
    }
    const float* We = (const float*)d_in[26];
    const float* Wh = (const float*)d_in[27];
    const float* bh = (const float*)d_in[28];
    float* out = (float*)d_out;

    // workspace carve (float units). Peak ~86 MB (< 104 MB proven in R0).
    float* ws   = (float*)d_ws;
    float* cat  = ws;                                   // 8,388,608 (B,512,N); stage4 Y reuses
    float* qbuf = cat + (long)8388608;                  // 8,388,608 multi-purpose
    float* pbuf = qbuf + (long)8388608;                 // 4,194,304 (p-values)
    int*   idxb = (int*)(pbuf + 4194304);               // 327,680 ints
    float* xt   = (float*)(idxb + 327680);              // 49,152
    float* xx   = xt + 49152;                           // 16,384
    unsigned short* Wqh = (unsigned short*)(xx + 16384);// 32,768 shorts each
    unsigned short* Wql = Wqh + 32768;
    unsigned short* Wph = Wql + 32768;
    unsigned short* Wpl = Wph + 32768;
    unsigned short* W4h = Wpl + 32768;                  // 262,144 shorts
    unsigned short* W4l = W4h + 262144;
    float* shf  = (float*)(W4l + 262144);               // 512
    float* ymax = shf + 512;                            // 2,048
    // qbuf internal layout:
    //  [0 .. 2,097,152) floats: Ghi/Glo (per-stage bf16 hi/lo, KDP<=128)
    //  [2,097,152 ..): knn slice lists (dead before qv written)
    //  [2,097,152 .. 6,291,456): qv (q-values, point-major)  [after knn]
    //  stage4: whole qbuf = catT hi (16MB) + catT lo (16MB)
    unsigned short* Ghi = (unsigned short*)qbuf;        // 2,097,152 shorts max
    unsigned short* Glo = Ghi + 2097152;
    float* knnd = qbuf + 2097152;                       // 1,310,720 floats
    int*   knni = (int*)(qbuf + 2097152 + 1310720);     // 1,310,720 ints
    float* qv   = qbuf + 2097152;                       // 4,194,304 floats (after knn)
    unsigned short* CTh = (unsigned short*)qbuf;        // 8,388,608 shorts
    unsigned short* CTl = CTh + 8388608;

    // ---- prep ----
    prep_xt_kernel<<<dim3(192), dim3(256), 0, stream>>>(x, xt);

    // ---- stage 0: knn on coords (C=3, K padded to 32) ----
    sqnorm_kernel<<<dim3(16, NB), dim3(256), 0, stream>>>(xt, xx, 3, (long)3 * N_PTS);
    to_bf16_tr<<<dim3(64, NB), dim3(256), 0, stream>>>(
        xt, (long)3 * N_PTS, 3, 32, Ghi, Glo);
    fused_knn_mfma3<32><<<dim3(64, NSL, NB), dim3(256), 0, stream>>>(
        Ghi, Glo, xx, knnd, knni);
    knn_merge4<<<dim3(64), dim3(256), 0, stream>>>(knnd, knni, idxb);
    edge0_kernel<<<dim3(N_PTS / 4, NB), dim3(64, 4), 0, stream>>>(
        xt, idxb, W[0], g[0], bb[0], m[0], v[0], cat);

    // ---- stages 1..3 ----
    const int Cs_[3]   = {64, 64, 128};
    const int co_[3]   = {64, 128, 256};
    const int inO_[3]  = {0, 64, 128};
    const int outO_[3] = {64, 128, 256};
    for (int s = 0; s < 3; s++) {
        int C = Cs_[s], cout = co_[s];
        const float* F = cat + (long)inO_[s] * N_PTS;   // batch stride 512*N
        sqnorm_kernel<<<dim3(16, NB), dim3(256), 0, stream>>>(F, xx, C, (long)512 * N_PTS);
        to_bf16_tr<<<dim3(64, NB), dim3(256), 0, stream>>>(
            F, (long)512 * N_PTS, C, C, Ghi, Glo);
        if (C == 64)
            fused_knn_mfma3<64><<<dim3(64, NSL, NB), dim3(256), 0, stream>>>(
                Ghi, Glo, xx, knnd, knni);
        else
            fused_knn_mfma3<128><<<dim3(64, NSL, NB), dim3(256), 0, stream>>>(
                Ghi, Glo, xx, knnd, knni);
        knn_merge4<<<dim3(64), dim3(256), 0, stream>>>(knnd, knni, idxb);

        int li = s + 1;
        fold_edge_bf16<<<dim3((C * cout + 255) / 256), dim3(256), 0, stream>>>(
            W[li], g[li], bb[li], m[li], v[li], Wqh, Wql, Wph, Wpl, shf, C, cout);
        if (C == 64)
            qp_mfma<64><<<dim3(64, cout / 64, NB), dim3(256), 0, stream>>>(
                Ghi, Glo, Wqh, Wql, Wph, Wpl, shf, qv, pbuf, cout);
        else
            qp_mfma<128><<<dim3(64, cout / 64, NB), dim3(256), 0, stream>>>(
                Ghi, Glo, Wqh, Wql, Wph, Wpl, shf, qv, pbuf, cout);
        gather_max_kernel<<<dim3(N_PTS / 4, NB), dim3(64, 4), 0, stream>>>(
            qv, pbuf, idxb, cat, cout, outO_[s]);
    }

    // ---- stage 4: MFMA pointwise conv + bn + lrelu ----
    fold_plain_bf16<<<dim3((512 * 512 + 255) / 256), dim3(256), 0, stream>>>(
        W[4], g[4], bb[4], m[4], v[4], W4h, W4l, shf, 512, 512);
    to_bf16_tr<<<dim3(64, NB), dim3(256), 0, stream>>>(
        cat, (long)512 * N_PTS, 512, 512, CTh, CTl);
    conv4_mfma<<<dim3(N_PTS / 16, NB), dim3(256), 0, stream>>>(
        CTh, CTl, W4h, W4l, shf, cat);   // Y overwrites dead fp32 cat

    // ---- global max + head ----
    rowmax_kernel<<<dim3(512, NB), dim3(256), 0, stream>>>(cat, ymax);
    head_kernel<<<dim3(NB), dim3(128), 0, stream>>>(ymax, We, Wh, bh, out);
}